// Round 1
// baseline (1791.853 us; speedup 1.0000x reference)
//
#include <hip/hip_runtime.h>

// Problem constants
// x: (8,256,64,64), w_off:(27,256,3,3), w_dcn:(256,256,3,3), w_ct:(256,256,4,4)
// out: (8,256,128,128) fp32

// ws layout (float offsets)
#define OFF_XT   0u
#define SZ_XT    (8u*64u*64u*256u)          // 8388608  x in NHWC
#define OFF_Y1   (OFF_XT + SZ_XT)           // 8388608  dcn out NHWC
#define SZ_Y1    SZ_XT
#define OFF_OM   (OFF_Y1 + SZ_Y1)           // 16777216 offset-conv out (8,27,64,64)
#define SZ_OM    (8u*27u*4096u)             // 884736
#define OFF_WD   (OFF_OM + SZ_OM)           // 17661952 w_dcn [k][ci][co]
#define SZ_WD    (9u*256u*256u)             // 589824
#define OFF_WC   (OFF_WD + SZ_WD)           // 18251776 w_ct [kr*4+kc][ci][co]
#define SZ_WC    (16u*256u*256u)            // 1048576
#define OFF_ST   (OFF_WC + SZ_WC)           // 19300352 stats: 2048 floats

__device__ __forceinline__ void fma4(float4& acc, float a, const float4 b) {
  acc.x = fmaf(a, b.x, acc.x);
  acc.y = fmaf(a, b.y, acc.y);
  acc.z = fmaf(a, b.z, acc.z);
  acc.w = fmaf(a, b.w, acc.w);
}

__global__ void k_init_om(const float* __restrict__ b_off, float* __restrict__ om) {
  int idx = blockIdx.x * 256 + threadIdx.x;
  if (idx < 8 * 27 * 4096) {
    int c = (idx >> 12) % 27;
    om[idx] = b_off[c];
  }
}

// NCHW -> NHWC transpose of x, per (n,y): 256(C) x 64(W) plane
__global__ __launch_bounds__(256) void k_transpose_x(const float* __restrict__ x,
                                                     float* __restrict__ xt) {
  __shared__ float tile[32][33];
  int ny = blockIdx.x;          // n*64 + y
  int n = ny >> 6, y = ny & 63;
  int c0 = blockIdx.y * 32;
  int w0 = blockIdx.z * 32;
  int t = threadIdx.x;
  int tx = t & 31, ty = t >> 5; // ty 0..7
#pragma unroll
  for (int i = 0; i < 4; ++i) {
    int c = c0 + ty + i * 8;
    tile[ty + i * 8][tx] = x[(((n * 256 + c) * 64 + y) << 6) + w0 + tx];
  }
  __syncthreads();
#pragma unroll
  for (int i = 0; i < 4; ++i) {
    int wl = ty + i * 8;
    xt[(((n * 64 + y) * 64 + (w0 + wl)) << 8) + c0 + tx] = tile[tx][wl];
  }
}

__global__ void k_transpose_wdcn(const float* __restrict__ w, float* __restrict__ wt) {
  int idx = blockIdx.x * 256 + threadIdx.x; // < 589824
  if (idx < 589824) {
    int co = idx & 255, ci = (idx >> 8) & 255, k = idx >> 16;
    wt[idx] = w[(co * 256 + ci) * 9 + k];
  }
}

__global__ void k_transpose_wct(const float* __restrict__ w, float* __restrict__ wt) {
  int idx = blockIdx.x * 256 + threadIdx.x; // < 1048576
  int co = idx & 255, ci = (idx >> 8) & 255, kk = idx >> 16;
  wt[idx] = w[(ci << 12) + (co << 4) + kk];
}

// 3x3 conv 256->27, SAME. grid (128, 8): (n*16+tile, ci-chunk of 32). atomicAdd into om.
__global__ __launch_bounds__(256) void k_offset_conv(const float* __restrict__ x,
                                                     const float* __restrict__ w_off,
                                                     float* __restrict__ om) {
  __shared__ float wl[32][9][27];
  __shared__ float xs[8][18 * 19];
  int bx = blockIdx.x;
  int n = bx >> 4;
  int tile = bx & 15;
  int ty0 = (tile >> 2) * 16, tx0 = (tile & 3) * 16;
  int ci0 = blockIdx.y * 32;
  int t = threadIdx.x;
  for (int i = t; i < 32 * 9 * 27; i += 256) {
    int ci = i / 243, r = i % 243, tap = r / 27, co = r % 27;
    wl[ci][tap][co] = w_off[(co * 256 + ci0 + ci) * 9 + tap];
  }
  float acc[27];
#pragma unroll
  for (int co = 0; co < 27; ++co) acc[co] = 0.f;
  int tx = t & 15, ty = t >> 4;
  for (int cig = 0; cig < 4; ++cig) {
    __syncthreads();
    for (int i = t; i < 8 * 324; i += 256) {
      int cc = i / 324, r2 = i % 324;
      int rr = r2 / 18, colc = r2 % 18;
      int yy = ty0 + rr - 1, xx = tx0 + colc - 1;
      float v = 0.f;
      if (yy >= 0 && yy < 64 && xx >= 0 && xx < 64)
        v = x[(((n * 256 + ci0 + cig * 8 + cc) * 64 + yy) << 6) + xx];
      xs[cc][rr * 19 + colc] = v;
    }
    __syncthreads();
    for (int cc = 0; cc < 8; ++cc) {
      int cil = cig * 8 + cc;
#pragma unroll
      for (int ky = 0; ky < 3; ++ky)
#pragma unroll
        for (int kx = 0; kx < 3; ++kx) {
          float v = xs[cc][(ty + ky) * 19 + tx + kx];
          int tap = ky * 3 + kx;
#pragma unroll
          for (int co = 0; co < 27; ++co) acc[co] += v * wl[cil][tap][co];
        }
    }
  }
  int yy = ty0 + ty, xx = tx0 + tx;
#pragma unroll
  for (int co = 0; co < 27; ++co)
    atomicAdd(&om[(n * 27 + co) * 4096 + (yy << 6) + xx], acc[co]);
}

// DCN v2 main: grid 512 (n*64 + y). block 256. out y1t NHWC.
// thread: pg=t>>4 (4 positions), cg=t&15 (co = cg*4 + q*64 quads)
__global__ __launch_bounds__(256) void k_dcn(const float* __restrict__ xt,
                                             const float* __restrict__ om,
                                             const float* __restrict__ wdcnT,
                                             const float* __restrict__ b_dcn,
                                             float* __restrict__ y1t) {
  __shared__ float w_lds[32 * 256];
  __shared__ float v_lds[32 * 64];
  __shared__ int p_y0[64], p_y1[64], p_x0[64], p_x1[64];
  __shared__ float p_w[64][4];
  int bid = blockIdx.x;
  int n = bid >> 6, y = bid & 63;
  int t = threadIdx.x;
  int pg = t >> 4, cg = t & 15;
  float4 facc[4][4];
#pragma unroll
  for (int i = 0; i < 4; ++i)
#pragma unroll
    for (int j = 0; j < 4; ++j) facc[i][j] = make_float4(0.f, 0.f, 0.f, 0.f);

  for (int k = 0; k < 9; ++k) {
    int ki = k / 3, kj = k % 3;
    __syncthreads();
    if (t < 64) {
      int p = t;
      const float* omn = om + (n * 27) * 4096 + (y << 6) + p;
      float offy = omn[(2 * k) * 4096];
      float offx = omn[(2 * k + 1) * 4096];
      float mv = omn[(18 + k) * 4096];
      float mask = 1.f / (1.f + expf(-mv));
      float ysf = (float)(y + ki - 1) + offy;
      float xsf = (float)(p + kj - 1) + offx;
      float y0f = floorf(ysf), x0f = floorf(xsf);
      float dy = ysf - y0f, dx = xsf - x0f;
      int y0 = (int)y0f, x0 = (int)x0f;
      int y1c = y0 + 1, x1c = x0 + 1;
      float v00 = (y0 >= 0 && y0 < 64 && x0 >= 0 && x0 < 64) ? 1.f : 0.f;
      float v01 = (y0 >= 0 && y0 < 64 && x1c >= 0 && x1c < 64) ? 1.f : 0.f;
      float v10 = (y1c >= 0 && y1c < 64 && x0 >= 0 && x0 < 64) ? 1.f : 0.f;
      float v11 = (y1c >= 0 && y1c < 64 && x1c >= 0 && x1c < 64) ? 1.f : 0.f;
      p_y0[p] = min(max(y0, 0), 63);
      p_y1[p] = min(max(y1c, 0), 63);
      p_x0[p] = min(max(x0, 0), 63);
      p_x1[p] = min(max(x1c, 0), 63);
      p_w[p][0] = (1.f - dy) * (1.f - dx) * mask * v00;
      p_w[p][1] = (1.f - dy) * dx * mask * v01;
      p_w[p][2] = dy * (1.f - dx) * mask * v10;
      p_w[p][3] = dy * dx * mask * v11;
    }
    for (int chunk = 0; chunk < 8; ++chunk) {
      int ci0 = chunk * 32;
      __syncthreads();
      // stage w: 32ci x 256co
      const float* wsrc = wdcnT + k * 65536 + ci0 * 256;
#pragma unroll
      for (int ii = 0; ii < 8; ++ii) {
        int o = t * 32 + ii * 4;
        *(float4*)&w_lds[o] = *(const float4*)&wsrc[o];
      }
      // stage v: 64 pos x 32 ci
      {
        int p = t >> 2, q = t & 3;
        int y0 = p_y0[p], y1c = p_y1[p], x0 = p_x0[p], x1c = p_x1[p];
        float w0 = p_w[p][0], w1 = p_w[p][1], w2 = p_w[p][2], w3 = p_w[p][3];
        int nb = n << 12;
        const float* a00 = xt + ((nb + (y0 << 6) + x0) << 8) + ci0 + q * 8;
        const float* a01 = xt + ((nb + (y0 << 6) + x1c) << 8) + ci0 + q * 8;
        const float* a10 = xt + ((nb + (y1c << 6) + x0) << 8) + ci0 + q * 8;
        const float* a11 = xt + ((nb + (y1c << 6) + x1c) << 8) + ci0 + q * 8;
        float4 c00a = *(const float4*)a00, c00b = *(const float4*)(a00 + 4);
        float4 c01a = *(const float4*)a01, c01b = *(const float4*)(a01 + 4);
        float4 c10a = *(const float4*)a10, c10b = *(const float4*)(a10 + 4);
        float4 c11a = *(const float4*)a11, c11b = *(const float4*)(a11 + 4);
        float va[8];
        va[0] = w0 * c00a.x + w1 * c01a.x + w2 * c10a.x + w3 * c11a.x;
        va[1] = w0 * c00a.y + w1 * c01a.y + w2 * c10a.y + w3 * c11a.y;
        va[2] = w0 * c00a.z + w1 * c01a.z + w2 * c10a.z + w3 * c11a.z;
        va[3] = w0 * c00a.w + w1 * c01a.w + w2 * c10a.w + w3 * c11a.w;
        va[4] = w0 * c00b.x + w1 * c01b.x + w2 * c10b.x + w3 * c11b.x;
        va[5] = w0 * c00b.y + w1 * c01b.y + w2 * c10b.y + w3 * c11b.y;
        va[6] = w0 * c00b.z + w1 * c01b.z + w2 * c10b.z + w3 * c11b.z;
        va[7] = w0 * c00b.w + w1 * c01b.w + w2 * c10b.w + w3 * c11b.w;
#pragma unroll
        for (int jj = 0; jj < 8; ++jj) v_lds[(q * 8 + jj) * 64 + p] = va[jj];
      }
      __syncthreads();
#pragma unroll 4
      for (int ci = 0; ci < 32; ++ci) {
        float4 av = *(float4*)&v_lds[(ci << 6) + (pg << 2)];
        const float* wr = &w_lds[(ci << 8) + (cg << 2)];
        float4 b0 = *(const float4*)&wr[0];
        float4 b1 = *(const float4*)&wr[64];
        float4 b2 = *(const float4*)&wr[128];
        float4 b3 = *(const float4*)&wr[192];
        fma4(facc[0][0], av.x, b0); fma4(facc[0][1], av.x, b1);
        fma4(facc[0][2], av.x, b2); fma4(facc[0][3], av.x, b3);
        fma4(facc[1][0], av.y, b0); fma4(facc[1][1], av.y, b1);
        fma4(facc[1][2], av.y, b2); fma4(facc[1][3], av.y, b3);
        fma4(facc[2][0], av.z, b0); fma4(facc[2][1], av.z, b1);
        fma4(facc[2][2], av.z, b2); fma4(facc[2][3], av.z, b3);
        fma4(facc[3][0], av.w, b0); fma4(facc[3][1], av.w, b1);
        fma4(facc[3][2], av.w, b2); fma4(facc[3][3], av.w, b3);
      }
    }
  }
  // epilogue: y1t[(n,y,p),co], co quads at cg*4 + q*64
#pragma unroll
  for (int i = 0; i < 4; ++i) {
    int p = pg * 4 + i;
    float* dst = y1t + (((n << 12) + (y << 6) + p) << 8);
#pragma unroll
    for (int q = 0; q < 4; ++q) {
      int cob = (cg << 2) + (q << 6);
      float4 val = facc[i][q];
      const float4 bi = *(const float4*)&b_dcn[cob];
      val.x += bi.x; val.y += bi.y; val.z += bi.z; val.w += bi.w;
      *(float4*)&dst[cob] = val;
    }
  }
}

// stats over channel-last buffer, rows of 256
__global__ void k_stats_cl(const float* __restrict__ buf, float* __restrict__ sums) {
  int t = threadIdx.x;
  int r0 = blockIdx.x * 64;
  float s = 0.f, q = 0.f;
  for (int r = 0; r < 64; ++r) {
    float v = buf[(r0 + r) * 256 + t];
    s += v; q += v * v;
  }
  atomicAdd(&sums[t], s);
  atomicAdd(&sums[256 + t], q);
}

__global__ void k_finalize(const float* __restrict__ sums, const float* __restrict__ gamma,
                           const float* __restrict__ beta, float* __restrict__ scsh,
                           float inv_cnt) {
  int t = threadIdx.x;
  float mu = sums[t] * inv_cnt;
  float var = sums[256 + t] * inv_cnt - mu * mu;
  float r = rsqrtf(var + 1e-5f);
  float sc = gamma[t] * r;
  scsh[t] = sc;
  scsh[256 + t] = beta[t] - mu * sc;
}

__global__ void k_norm_cl(float* __restrict__ buf, const float* __restrict__ scsh) {
  int idx = blockIdx.x * 256 + threadIdx.x; // float4 index
  int co4 = idx & 63;
  float4 v = *(float4*)&buf[(size_t)idx * 4];
  float4 sc = *(const float4*)&scsh[co4 * 4];
  float4 sh = *(const float4*)&scsh[256 + co4 * 4];
  v.x = fmaxf(fmaf(v.x, sc.x, sh.x), 0.f);
  v.y = fmaxf(fmaf(v.y, sc.y, sh.y), 0.f);
  v.z = fmaxf(fmaf(v.z, sc.z, sh.z), 0.f);
  v.w = fmaxf(fmaf(v.w, sc.w, sh.w), 0.f);
  *(float4*)&buf[(size_t)idx * 4] = v;
}

// ConvTranspose 4x4 s2 p1 as 4 parity classes of 2x2-tap convs.
// grid (512, 4): (n*64+u, class). out NCHW raw (pre-BN2).
__global__ __launch_bounds__(256) void k_convt(const float* __restrict__ y1t,
                                               const float* __restrict__ wctT,
                                               float* __restrict__ out) {
  __shared__ float w_lds[4 * 8 * 256]; // [tap][ci][co]
  __shared__ float rows[2][8][68];     // [row][ci][col]
  int bx = blockIdx.x;
  int n = bx >> 6, u = bx & 63;
  int cls = blockIdx.y;
  int py = cls >> 1, px = cls & 1;
  int iyA = (py == 0) ? u - 1 : u;
  int iyB = (py == 0) ? u : u + 1;
  int krA = (py == 0) ? 3 : 2;
  int krB = (py == 0) ? 1 : 0;
  int kc0 = (px == 0) ? 3 : 2;
  int kc1 = kc0 - 2;
  int colbase = (px == 0) ? -1 : 0;
  bool vA = (iyA >= 0 && iyA < 64);
  bool vB = (iyB >= 0 && iyB < 64);
  int t = threadIdx.x;
  int pg = t >> 4, cg = t & 15;
  float4 facc[4][4];
#pragma unroll
  for (int i = 0; i < 4; ++i)
#pragma unroll
    for (int j = 0; j < 4; ++j) facc[i][j] = make_float4(0.f, 0.f, 0.f, 0.f);
  int kidx[4];
  kidx[0] = (krA * 4 + kc0) << 16;
  kidx[1] = (krA * 4 + kc1) << 16;
  kidx[2] = (krB * 4 + kc0) << 16;
  kidx[3] = (krB * 4 + kc1) << 16;

  for (int chunk = 0; chunk < 32; ++chunk) {
    int ci0 = chunk * 8;
    __syncthreads();
#pragma unroll
    for (int ii = 0; ii < 8; ++ii) {
      int o = t * 32 + ii * 4;
      int tap = o >> 11;
      int rem = o & 2047;
      int ci = rem >> 8;
      int co = rem & 255;
      *(float4*)&w_lds[o] = *(const float4*)&wctT[kidx[tap] + (ci0 + ci) * 256 + co];
    }
    {
      int half = t & 1;
      for (int pair = t >> 1; pair < 132; pair += 128) {
        int row = pair / 66, c = pair % 66;
        int ix = colbase + c;
        int iy = (row == 0) ? iyA : iyB;
        bool rv = (row == 0) ? vA : vB;
        float4 v4 = make_float4(0.f, 0.f, 0.f, 0.f);
        if (rv && ix >= 0 && ix < 64)
          v4 = *(const float4*)&y1t[(((n << 6) + iy) * 64 + ix) * 256 + ci0 + half * 4];
        rows[row][half * 4 + 0][c] = v4.x;
        rows[row][half * 4 + 1][c] = v4.y;
        rows[row][half * 4 + 2][c] = v4.z;
        rows[row][half * 4 + 3][c] = v4.w;
      }
    }
    __syncthreads();
    for (int ci = 0; ci < 8; ++ci) {
      float4 aA = *(float4*)&rows[0][ci][pg << 2];
      float eA = rows[0][ci][(pg << 2) + 4];
      float4 aB = *(float4*)&rows[1][ci][pg << 2];
      float eB = rows[1][ci][(pg << 2) + 4];
      // tap0: rowA tx0
      {
        const float* wp = &w_lds[(0 * 8 + ci) * 256 + (cg << 2)];
        float4 w0 = *(const float4*)&wp[0], w1 = *(const float4*)&wp[64];
        float4 w2 = *(const float4*)&wp[128], w3 = *(const float4*)&wp[192];
        fma4(facc[0][0], aA.x, w0); fma4(facc[0][1], aA.x, w1); fma4(facc[0][2], aA.x, w2); fma4(facc[0][3], aA.x, w3);
        fma4(facc[1][0], aA.y, w0); fma4(facc[1][1], aA.y, w1); fma4(facc[1][2], aA.y, w2); fma4(facc[1][3], aA.y, w3);
        fma4(facc[2][0], aA.z, w0); fma4(facc[2][1], aA.z, w1); fma4(facc[2][2], aA.z, w2); fma4(facc[2][3], aA.z, w3);
        fma4(facc[3][0], aA.w, w0); fma4(facc[3][1], aA.w, w1); fma4(facc[3][2], aA.w, w2); fma4(facc[3][3], aA.w, w3);
      }
      // tap1: rowA tx1 (shifted)
      {
        const float* wp = &w_lds[(1 * 8 + ci) * 256 + (cg << 2)];
        float4 w0 = *(const float4*)&wp[0], w1 = *(const float4*)&wp[64];
        float4 w2 = *(const float4*)&wp[128], w3 = *(const float4*)&wp[192];
        fma4(facc[0][0], aA.y, w0); fma4(facc[0][1], aA.y, w1); fma4(facc[0][2], aA.y, w2); fma4(facc[0][3], aA.y, w3);
        fma4(facc[1][0], aA.z, w0); fma4(facc[1][1], aA.z, w1); fma4(facc[1][2], aA.z, w2); fma4(facc[1][3], aA.z, w3);
        fma4(facc[2][0], aA.w, w0); fma4(facc[2][1], aA.w, w1); fma4(facc[2][2], aA.w, w2); fma4(facc[2][3], aA.w, w3);
        fma4(facc[3][0], eA,   w0); fma4(facc[3][1], eA,   w1); fma4(facc[3][2], eA,   w2); fma4(facc[3][3], eA,   w3);
      }
      // tap2: rowB tx0
      {
        const float* wp = &w_lds[(2 * 8 + ci) * 256 + (cg << 2)];
        float4 w0 = *(const float4*)&wp[0], w1 = *(const float4*)&wp[64];
        float4 w2 = *(const float4*)&wp[128], w3 = *(const float4*)&wp[192];
        fma4(facc[0][0], aB.x, w0); fma4(facc[0][1], aB.x, w1); fma4(facc[0][2], aB.x, w2); fma4(facc[0][3], aB.x, w3);
        fma4(facc[1][0], aB.y, w0); fma4(facc[1][1], aB.y, w1); fma4(facc[1][2], aB.y, w2); fma4(facc[1][3], aB.y, w3);
        fma4(facc[2][0], aB.z, w0); fma4(facc[2][1], aB.z, w1); fma4(facc[2][2], aB.z, w2); fma4(facc[2][3], aB.z, w3);
        fma4(facc[3][0], aB.w, w0); fma4(facc[3][1], aB.w, w1); fma4(facc[3][2], aB.w, w2); fma4(facc[3][3], aB.w, w3);
      }
      // tap3: rowB tx1 (shifted)
      {
        const float* wp = &w_lds[(3 * 8 + ci) * 256 + (cg << 2)];
        float4 w0 = *(const float4*)&wp[0], w1 = *(const float4*)&wp[64];
        float4 w2 = *(const float4*)&wp[128], w3 = *(const float4*)&wp[192];
        fma4(facc[0][0], aB.y, w0); fma4(facc[0][1], aB.y, w1); fma4(facc[0][2], aB.y, w2); fma4(facc[0][3], aB.y, w3);
        fma4(facc[1][0], aB.z, w0); fma4(facc[1][1], aB.z, w1); fma4(facc[1][2], aB.z, w2); fma4(facc[1][3], aB.z, w3);
        fma4(facc[2][0], aB.w, w0); fma4(facc[2][1], aB.w, w1); fma4(facc[2][2], aB.w, w2); fma4(facc[2][3], aB.w, w3);
        fma4(facc[3][0], eB,   w0); fma4(facc[3][1], eB,   w1); fma4(facc[3][2], eB,   w2); fma4(facc[3][3], eB,   w3);
      }
    }
  }
  int oy = 2 * u + py;
#pragma unroll
  for (int i = 0; i < 4; ++i) {
    int v = pg * 4 + i;
    int ox = 2 * v + px;
#pragma unroll
    for (int q = 0; q < 4; ++q) {
      int cob = (cg << 2) + (q << 6);
      float4 val = facc[i][q];
      out[(((n << 8) + cob + 0) * 128 + oy) * 128 + ox] = val.x;
      out[(((n << 8) + cob + 1) * 128 + oy) * 128 + ox] = val.y;
      out[(((n << 8) + cob + 2) * 128 + oy) * 128 + ox] = val.z;
      out[(((n << 8) + cob + 3) * 128 + oy) * 128 + ox] = val.w;
    }
  }
}

// stats over NCHW buffer, one block per (n,c): 16384 contiguous
__global__ void k_stats_nchw(const float* __restrict__ buf, float* __restrict__ sums) {
  __shared__ float red[256];
  int b = blockIdx.x;
  int c = b & 255;
  int t = threadIdx.x;
  const float* p = buf + (size_t)b * 16384;
  float s = 0.f, q = 0.f;
  for (int i = t; i < 16384; i += 256) {
    float v = p[i];
    s += v; q += v * v;
  }
  red[t] = s; __syncthreads();
  for (int w = 128; w > 0; w >>= 1) { if (t < w) red[t] += red[t + w]; __syncthreads(); }
  float ts = red[0];
  __syncthreads();
  red[t] = q; __syncthreads();
  for (int w = 128; w > 0; w >>= 1) { if (t < w) red[t] += red[t + w]; __syncthreads(); }
  if (t == 0) { atomicAdd(&sums[c], ts); atomicAdd(&sums[256 + c], red[0]); }
}

__global__ void k_norm_nchw(float* __restrict__ buf, const float* __restrict__ scsh) {
  int idx = blockIdx.x * 256 + threadIdx.x; // float4 index
  int c = (idx >> 12) & 255;
  float sc = scsh[c], sh = scsh[256 + c];
  float4 v = *(float4*)&buf[(size_t)idx * 4];
  v.x = fmaxf(fmaf(v.x, sc, sh), 0.f);
  v.y = fmaxf(fmaf(v.y, sc, sh), 0.f);
  v.z = fmaxf(fmaf(v.z, sc, sh), 0.f);
  v.w = fmaxf(fmaf(v.w, sc, sh), 0.f);
  *(float4*)&buf[(size_t)idx * 4] = v;
}

extern "C" void kernel_launch(void* const* d_in, const int* in_sizes, int n_in,
                              void* d_out, int out_size, void* d_ws, size_t ws_size,
                              hipStream_t stream) {
  (void)in_sizes; (void)n_in; (void)out_size; (void)ws_size;
  const float* x      = (const float*)d_in[0];
  const float* w_off  = (const float*)d_in[1];
  const float* b_off  = (const float*)d_in[2];
  const float* w_dcn  = (const float*)d_in[3];
  const float* b_dcn  = (const float*)d_in[4];
  const float* gamma1 = (const float*)d_in[5];
  const float* beta1  = (const float*)d_in[6];
  const float* w_ct   = (const float*)d_in[7];
  const float* gamma2 = (const float*)d_in[8];
  const float* beta2  = (const float*)d_in[9];
  float* ws  = (float*)d_ws;
  float* xt  = ws + OFF_XT;
  float* y1  = ws + OFF_Y1;
  float* om  = ws + OFF_OM;
  float* wd  = ws + OFF_WD;
  float* wc  = ws + OFF_WC;
  float* st  = ws + OFF_ST;
  float* out = (float*)d_out;

  hipMemsetAsync(st, 0, 2048 * sizeof(float), stream);
  k_init_om<<<3456, 256, 0, stream>>>(b_off, om);
  k_transpose_x<<<dim3(512, 8, 2), 256, 0, stream>>>(x, xt);
  k_transpose_wdcn<<<2304, 256, 0, stream>>>(w_dcn, wd);
  k_transpose_wct<<<4096, 256, 0, stream>>>(w_ct, wc);
  k_offset_conv<<<dim3(128, 8), 256, 0, stream>>>(x, w_off, om);
  k_dcn<<<512, 256, 0, stream>>>(xt, om, wd, b_dcn, y1);
  k_stats_cl<<<512, 256, 0, stream>>>(y1, st);
  k_finalize<<<1, 256, 0, stream>>>(st, gamma1, beta1, st + 512, 1.f / 32768.f);
  k_norm_cl<<<8192, 256, 0, stream>>>(y1, st + 512);
  k_convt<<<dim3(512, 4), 256, 0, stream>>>(y1, wc, out);
  k_stats_nchw<<<2048, 256, 0, stream>>>(out, st + 1024);
  k_finalize<<<1, 256, 0, stream>>>(st + 1024, gamma2, beta2, st + 1536, 1.f / 131072.f);
  k_norm_nchw<<<32768, 256, 0, stream>>>(out, st + 1536);
}

// Round 3
// 923.270 us; speedup vs baseline: 1.9408x; 1.9408x over previous
//
#include <hip/hip_runtime.h>

// Problem constants
// x: (8,256,64,64), w_off:(27,256,3,3), w_dcn:(256,256,3,3), w_ct:(256,256,4,4)
// out: (8,256,128,128) fp32

// ws layout (float offsets)
#define OFF_XT   0u
#define SZ_XT    (8u*64u*64u*256u)          // 8388608  x in NHWC (dead after k_dcn; y1b bf16 reuses it)
#define OFF_Y1   (OFF_XT + SZ_XT)           // 8388608  dcn out NHWC fp32
#define SZ_Y1    SZ_XT
#define OFF_OM   (OFF_Y1 + SZ_Y1)           // 16777216 offset-conv out (8,27,64,64)
#define SZ_OM    (8u*27u*4096u)             // 884736
#define OFF_WD   (OFF_OM + SZ_OM)           // 17661952 w_dcn [k][ci][co]
#define SZ_WD    (9u*256u*256u)             // 589824
#define OFF_WC   (OFF_WD + SZ_WD)           // 18251776 wcb bf16 packed (524288 floats used)
#define SZ_WC    (16u*256u*256u)            // 1048576
#define OFF_ST   (OFF_WC + SZ_WC)           // 19300352 stats: 2048 floats

typedef __attribute__((ext_vector_type(8))) short bf16x8;
typedef __attribute__((ext_vector_type(4))) float f32x4;

__device__ __forceinline__ void fma4(float4& acc, float a, const float4 b) {
  acc.x = fmaf(a, b.x, acc.x);
  acc.y = fmaf(a, b.y, acc.y);
  acc.z = fmaf(a, b.z, acc.z);
  acc.w = fmaf(a, b.w, acc.w);
}

__device__ __forceinline__ unsigned short f2bf(float f) {
  unsigned int u = __float_as_uint(f);
  u += 0x7fffu + ((u >> 16) & 1u);
  return (unsigned short)(u >> 16);
}

__global__ void k_init_om(const float* __restrict__ b_off, float* __restrict__ om) {
  int idx = blockIdx.x * 256 + threadIdx.x;
  if (idx < 8 * 27 * 4096) {
    int c = (idx >> 12) % 27;
    om[idx] = b_off[c];
  }
}

// NCHW -> NHWC transpose of x, per (n,y): 256(C) x 64(W) plane
__global__ __launch_bounds__(256) void k_transpose_x(const float* __restrict__ x,
                                                     float* __restrict__ xt) {
  __shared__ float tile[32][33];
  int ny = blockIdx.x;          // n*64 + y
  int n = ny >> 6, y = ny & 63;
  int c0 = blockIdx.y * 32;
  int w0 = blockIdx.z * 32;
  int t = threadIdx.x;
  int tx = t & 31, ty = t >> 5; // ty 0..7
#pragma unroll
  for (int i = 0; i < 4; ++i) {
    int c = c0 + ty + i * 8;
    tile[ty + i * 8][tx] = x[(((n * 256 + c) * 64 + y) << 6) + w0 + tx];
  }
  __syncthreads();
#pragma unroll
  for (int i = 0; i < 4; ++i) {
    int wl = ty + i * 8;
    xt[(((n * 64 + y) * 64 + (w0 + wl)) << 8) + c0 + tx] = tile[tx][wl];
  }
}

__global__ void k_transpose_wdcn(const float* __restrict__ w, float* __restrict__ wt) {
  int idx = blockIdx.x * 256 + threadIdx.x; // < 589824
  if (idx < 589824) {
    int co = idx & 255, ci = (idx >> 8) & 255, k = idx >> 16;
    wt[idx] = w[(co * 256 + ci) * 9 + k];
  }
}

// w_ct -> bf16 packed [py][px][tap][chunk][co 256][ci 32]
__global__ void k_prep_wct(const float* __restrict__ w, unsigned short* __restrict__ wcb) {
  int idx = blockIdx.x * 256 + threadIdx.x; // < 1048576
  int cil = idx & 31;
  int co = (idx >> 5) & 255;
  int chunk = (idx >> 13) & 7;
  int tap = (idx >> 16) & 3;
  int px = (idx >> 18) & 1;
  int py = (idx >> 19) & 1;
  int ci = chunk * 32 + cil;
  int krA = (py == 0) ? 3 : 2, krB = (py == 0) ? 1 : 0;
  int kc0 = (px == 0) ? 3 : 2, kc1 = kc0 - 2;
  int kr = (tap < 2) ? krA : krB;
  int kc = (tap & 1) ? kc1 : kc0;
  float v = w[(ci << 12) + (co << 4) + kr * 4 + kc];
  wcb[idx] = f2bf(v);
}

// 3x3 conv 256->27, SAME. grid (128, 8): (n*16+tile, ci-chunk of 32). atomicAdd into om.
__global__ __launch_bounds__(256) void k_offset_conv(const float* __restrict__ x,
                                                     const float* __restrict__ w_off,
                                                     float* __restrict__ om) {
  __shared__ float wl[32][9][27];
  __shared__ float xs[8][18 * 19];
  int bx = blockIdx.x;
  int n = bx >> 4;
  int tile = bx & 15;
  int ty0 = (tile >> 2) * 16, tx0 = (tile & 3) * 16;
  int ci0 = blockIdx.y * 32;
  int t = threadIdx.x;
  for (int i = t; i < 32 * 9 * 27; i += 256) {
    int ci = i / 243, r = i % 243, tap = r / 27, co = r % 27;
    wl[ci][tap][co] = w_off[(co * 256 + ci0 + ci) * 9 + tap];
  }
  float acc[27];
#pragma unroll
  for (int co = 0; co < 27; ++co) acc[co] = 0.f;
  int tx = t & 15, ty = t >> 4;
  for (int cig = 0; cig < 4; ++cig) {
    __syncthreads();
    for (int i = t; i < 8 * 324; i += 256) {
      int cc = i / 324, r2 = i % 324;
      int rr = r2 / 18, colc = r2 % 18;
      int yy = ty0 + rr - 1, xx = tx0 + colc - 1;
      float v = 0.f;
      if (yy >= 0 && yy < 64 && xx >= 0 && xx < 64)
        v = x[(((n * 256 + ci0 + cig * 8 + cc) * 64 + yy) << 6) + xx];
      xs[cc][rr * 19 + colc] = v;
    }
    __syncthreads();
    for (int cc = 0; cc < 8; ++cc) {
      int cil = cig * 8 + cc;
#pragma unroll
      for (int ky = 0; ky < 3; ++ky)
#pragma unroll
        for (int kx = 0; kx < 3; ++kx) {
          float v = xs[cc][(ty + ky) * 19 + tx + kx];
          int tap = ky * 3 + kx;
#pragma unroll
          for (int co = 0; co < 27; ++co) acc[co] += v * wl[cil][tap][co];
        }
    }
  }
  int yy = ty0 + ty, xx = tx0 + tx;
#pragma unroll
  for (int co = 0; co < 27; ++co)
    atomicAdd(&om[(n * 27 + co) * 4096 + (yy << 6) + xx], acc[co]);
}

// DCN v2 main: grid 512 (n*64 + y). block 256. out y1t NHWC.
__global__ __launch_bounds__(256) void k_dcn(const float* __restrict__ xt,
                                             const float* __restrict__ om,
                                             const float* __restrict__ wdcnT,
                                             const float* __restrict__ b_dcn,
                                             float* __restrict__ y1t) {
  __shared__ float w_lds[32 * 256];
  __shared__ float v_lds[32 * 64];
  __shared__ int p_y0[64], p_y1[64], p_x0[64], p_x1[64];
  __shared__ float p_w[64][4];
  int bid = blockIdx.x;
  int n = bid >> 6, y = bid & 63;
  int t = threadIdx.x;
  int pg = t >> 4, cg = t & 15;
  float4 facc[4][4];
#pragma unroll
  for (int i = 0; i < 4; ++i)
#pragma unroll
    for (int j = 0; j < 4; ++j) facc[i][j] = make_float4(0.f, 0.f, 0.f, 0.f);

  for (int k = 0; k < 9; ++k) {
    int ki = k / 3, kj = k % 3;
    __syncthreads();
    if (t < 64) {
      int p = t;
      const float* omn = om + (n * 27) * 4096 + (y << 6) + p;
      float offy = omn[(2 * k) * 4096];
      float offx = omn[(2 * k + 1) * 4096];
      float mv = omn[(18 + k) * 4096];
      float mask = 1.f / (1.f + expf(-mv));
      float ysf = (float)(y + ki - 1) + offy;
      float xsf = (float)(p + kj - 1) + offx;
      float y0f = floorf(ysf), x0f = floorf(xsf);
      float dy = ysf - y0f, dx = xsf - x0f;
      int y0 = (int)y0f, x0 = (int)x0f;
      int y1c = y0 + 1, x1c = x0 + 1;
      float v00 = (y0 >= 0 && y0 < 64 && x0 >= 0 && x0 < 64) ? 1.f : 0.f;
      float v01 = (y0 >= 0 && y0 < 64 && x1c >= 0 && x1c < 64) ? 1.f : 0.f;
      float v10 = (y1c >= 0 && y1c < 64 && x0 >= 0 && x0 < 64) ? 1.f : 0.f;
      float v11 = (y1c >= 0 && y1c < 64 && x1c >= 0 && x1c < 64) ? 1.f : 0.f;
      p_y0[p] = min(max(y0, 0), 63);
      p_y1[p] = min(max(y1c, 0), 63);
      p_x0[p] = min(max(x0, 0), 63);
      p_x1[p] = min(max(x1c, 0), 63);
      p_w[p][0] = (1.f - dy) * (1.f - dx) * mask * v00;
      p_w[p][1] = (1.f - dy) * dx * mask * v01;
      p_w[p][2] = dy * (1.f - dx) * mask * v10;
      p_w[p][3] = dy * dx * mask * v11;
    }
    for (int chunk = 0; chunk < 8; ++chunk) {
      int ci0 = chunk * 32;
      __syncthreads();
      // stage w: 32ci x 256co — linear coalesced copy (conflict-free)
      const float* wsrc = wdcnT + k * 65536 + ci0 * 256;
#pragma unroll
      for (int ii = 0; ii < 8; ++ii) {
        int o = ii * 1024 + t * 4;
        *(float4*)&w_lds[o] = *(const float4*)&wsrc[o];
      }
      // stage v: 64 pos x 32 ci
      {
        int p = t >> 2, q = t & 3;
        int y0 = p_y0[p], y1c = p_y1[p], x0 = p_x0[p], x1c = p_x1[p];
        float w0 = p_w[p][0], w1 = p_w[p][1], w2 = p_w[p][2], w3 = p_w[p][3];
        int nb = n << 12;
        const float* a00 = xt + ((nb + (y0 << 6) + x0) << 8) + ci0 + q * 8;
        const float* a01 = xt + ((nb + (y0 << 6) + x1c) << 8) + ci0 + q * 8;
        const float* a10 = xt + ((nb + (y1c << 6) + x0) << 8) + ci0 + q * 8;
        const float* a11 = xt + ((nb + (y1c << 6) + x1c) << 8) + ci0 + q * 8;
        float4 c00a = *(const float4*)a00, c00b = *(const float4*)(a00 + 4);
        float4 c01a = *(const float4*)a01, c01b = *(const float4*)(a01 + 4);
        float4 c10a = *(const float4*)a10, c10b = *(const float4*)(a10 + 4);
        float4 c11a = *(const float4*)a11, c11b = *(const float4*)(a11 + 4);
        float va[8];
        va[0] = w0 * c00a.x + w1 * c01a.x + w2 * c10a.x + w3 * c11a.x;
        va[1] = w0 * c00a.y + w1 * c01a.y + w2 * c10a.y + w3 * c11a.y;
        va[2] = w0 * c00a.z + w1 * c01a.z + w2 * c10a.z + w3 * c11a.z;
        va[3] = w0 * c00a.w + w1 * c01a.w + w2 * c10a.w + w3 * c11a.w;
        va[4] = w0 * c00b.x + w1 * c01b.x + w2 * c10b.x + w3 * c11b.x;
        va[5] = w0 * c00b.y + w1 * c01b.y + w2 * c10b.y + w3 * c11b.y;
        va[6] = w0 * c00b.z + w1 * c01b.z + w2 * c10b.z + w3 * c11b.z;
        va[7] = w0 * c00b.w + w1 * c01b.w + w2 * c10b.w + w3 * c11b.w;
#pragma unroll
        for (int jj = 0; jj < 8; ++jj) v_lds[(q * 8 + jj) * 64 + p] = va[jj];
      }
      __syncthreads();
#pragma unroll 4
      for (int ci = 0; ci < 32; ++ci) {
        float4 av = *(float4*)&v_lds[(ci << 6) + (pg << 2)];
        const float* wr = &w_lds[(ci << 8) + (cg << 2)];
        float4 b0 = *(const float4*)&wr[0];
        float4 b1 = *(const float4*)&wr[64];
        float4 b2 = *(const float4*)&wr[128];
        float4 b3 = *(const float4*)&wr[192];
        fma4(facc[0][0], av.x, b0); fma4(facc[0][1], av.x, b1);
        fma4(facc[0][2], av.x, b2); fma4(facc[0][3], av.x, b3);
        fma4(facc[1][0], av.y, b0); fma4(facc[1][1], av.y, b1);
        fma4(facc[1][2], av.y, b2); fma4(facc[1][3], av.y, b3);
        fma4(facc[2][0], av.z, b0); fma4(facc[2][1], av.z, b1);
        fma4(facc[2][2], av.z, b2); fma4(facc[2][3], av.z, b3);
        fma4(facc[3][0], av.w, b0); fma4(facc[3][1], av.w, b1);
        fma4(facc[3][2], av.w, b2); fma4(facc[3][3], av.w, b3);
      }
    }
  }
#pragma unroll
  for (int i = 0; i < 4; ++i) {
    int p = pg * 4 + i;
    float* dst = y1t + (((n << 12) + (y << 6) + p) << 8);
#pragma unroll
    for (int q = 0; q < 4; ++q) {
      int cob = (cg << 2) + (q << 6);
      float4 val = facc[i][q];
      const float4 bi = *(const float4*)&b_dcn[cob];
      val.x += bi.x; val.y += bi.y; val.z += bi.z; val.w += bi.w;
      *(float4*)&dst[cob] = val;
    }
  }
}

// stats over channel-last buffer, rows of 256
__global__ void k_stats_cl(const float* __restrict__ buf, float* __restrict__ sums) {
  int t = threadIdx.x;
  int r0 = blockIdx.x * 64;
  float s = 0.f, q = 0.f;
  for (int r = 0; r < 64; ++r) {
    float v = buf[(r0 + r) * 256 + t];
    s += v; q += v * v;
  }
  atomicAdd(&sums[t], s);
  atomicAdd(&sums[256 + t], q);
}

__global__ void k_finalize(const float* __restrict__ sums, const float* __restrict__ gamma,
                           const float* __restrict__ beta, float* __restrict__ scsh,
                           float inv_cnt) {
  int t = threadIdx.x;
  float mu = sums[t] * inv_cnt;
  float var = sums[256 + t] * inv_cnt - mu * mu;
  float r = rsqrtf(var + 1e-5f);
  float sc = gamma[t] * r;
  scsh[t] = sc;
  scsh[256 + t] = beta[t] - mu * sc;
}

// normalize+relu in place, and emit bf16 copy (NHWC) for the MFMA convT
__global__ void k_norm_cl(float* __restrict__ buf, const float* __restrict__ scsh,
                          unsigned short* __restrict__ y1b) {
  int idx = blockIdx.x * 256 + threadIdx.x; // float4 index
  int co4 = idx & 63;
  float4 v = *(float4*)&buf[(size_t)idx * 4];
  float4 sc = *(const float4*)&scsh[co4 * 4];
  float4 sh = *(const float4*)&scsh[256 + co4 * 4];
  v.x = fmaxf(fmaf(v.x, sc.x, sh.x), 0.f);
  v.y = fmaxf(fmaf(v.y, sc.y, sh.y), 0.f);
  v.z = fmaxf(fmaf(v.z, sc.z, sh.z), 0.f);
  v.w = fmaxf(fmaf(v.w, sc.w, sh.w), 0.f);
  *(float4*)&buf[(size_t)idx * 4] = v;
  uint2 p;
  p.x = (unsigned int)f2bf(v.x) | ((unsigned int)f2bf(v.y) << 16);
  p.y = (unsigned int)f2bf(v.z) | ((unsigned int)f2bf(v.w) << 16);
  *(uint2*)&y1b[(size_t)idx * 4] = p;
}

// ConvTranspose 4x4 s2 p1 via bf16 MFMA. grid (512, 2): (n*64+u, py). 512 threads (8 waves).
// Wave: px = wave>>2, co slice = (wave&3)*64. Output tile per block: full row oy=2u+py, 128 ox, 256 co.
__global__ __launch_bounds__(512) void k_convt_mfma(const unsigned short* __restrict__ y1b,
                                                    const unsigned short* __restrict__ wcb,
                                                    float* __restrict__ out) {
  // aLds: [r(2)][c(66)] rows of 40 ushort (32 data + 8 pad, 80B rows => 5c mod 8 bank spread)
  // wLds: [px(2)][co(256)] rows of 40 ushort
  __shared__ unsigned short sh[2 * 66 * 40 + 2 * 256 * 40]; // 51520 B
  unsigned short* aLds = sh;
  unsigned short* wLds = sh + 2 * 66 * 40;

  int bx = blockIdx.x;
  int n = bx >> 6, u = bx & 63;
  int py = blockIdx.y;
  int t = threadIdx.x;
  int wave = t >> 6, lane = t & 63;
  int px_w = wave >> 2, ns = wave & 3;
  int co_base = ns * 64;
  int l15 = lane & 15, l4 = lane >> 4;
  int iy[2];
  iy[0] = (py == 0) ? u - 1 : u;
  iy[1] = (py == 0) ? u : u + 1;
  bool rv[2] = {iy[0] >= 0 && iy[0] < 64, iy[1] >= 0 && iy[1] < 64};

  f32x4 acc[4][4] = {};

  for (int chunk = 0; chunk < 8; ++chunk) {
    int ci0 = chunk * 32;
    __syncthreads(); // previous chunk's reads of aLds done
    // stage A: tasks: r(2) x c(66) x slot(4) = 528
    for (int task = t; task < 528; task += 512) {
      int slot = task & 3;
      int c = (task >> 2) % 66;
      int r = task / 264;
      int ix = c - 1;
      uint4 val = make_uint4(0u, 0u, 0u, 0u);
      if (rv[r] && ix >= 0 && ix < 64)
        val = *(const uint4*)&y1b[((size_t)((n * 4096 + iy[r] * 64 + ix)) * 256 + ci0 + slot * 8)];
      *(uint4*)&aLds[(r * 66 + c) * 40 + slot * 8] = val;
    }
    for (int tap = 0; tap < 4; ++tap) {
      __syncthreads(); // A staged (tap0) / previous tap's wLds reads done
      // stage W: tasks: px(2) x co(256) x slot(4) = 2048
#pragma unroll
      for (int it = 0; it < 4; ++it) {
        int task = it * 512 + t;
        int slot = task & 3;
        int co = (task >> 2) & 255;
        int px = task >> 10;
        const unsigned short* src =
            wcb + ((size_t)((((py * 2 + px) * 4 + tap) * 8 + chunk) * 256 + co) * 32 + slot * 8);
        uint4 val = *(const uint4*)src;
        *(uint4*)&wLds[(px * 256 + co) * 40 + slot * 8] = val;
      }
      __syncthreads();
      int r = tap >> 1, s = tap & 1;
      bf16x8 b[4];
#pragma unroll
      for (int j = 0; j < 4; ++j)
        b[j] = *(bf16x8*)&wLds[(px_w * 256 + co_base + 16 * j + l15) * 40 + l4 * 8];
#pragma unroll
      for (int i = 0; i < 4; ++i) {
        int c = 16 * i + l15 + s + px_w;
        bf16x8 a = *(bf16x8*)&aLds[(r * 66 + c) * 40 + l4 * 8];
#pragma unroll
        for (int j = 0; j < 4; ++j)
          acc[i][j] = __builtin_amdgcn_mfma_f32_16x16x32_bf16(a, b[j], acc[i][j], 0, 0, 0);
      }
    }
  }

  // epilogue: interleave px via LDS, write contiguous 128-float rows.
  // epi: [co_l(64)][132] floats: [px*64 + v], row stride 132 floats (528B)
  float* epi = (float*)sh;
  int oy = 2 * u + py;
  for (int qt = 0; qt < 4; ++qt) {
    __syncthreads(); // previous use of sh done
    if (ns == qt) {
#pragma unroll
      for (int i = 0; i < 4; ++i)
#pragma unroll
        for (int j = 0; j < 4; ++j) {
          int co_l = 16 * j + l15;
          int vbase = 16 * i + l4 * 4;
          *(f32x4*)&epi[co_l * 132 + px_w * 64 + vbase] = acc[i][j];
        }
    }
    __syncthreads();
    // store: tasks co_l(64) x q(32) = 2048, q is the ox-quad (ox = 4q..4q+3)
#pragma unroll
    for (int it = 0; it < 4; ++it) {
      int task = it * 512 + t;
      int q = task & 31;
      int co_l = task >> 5;
      int co = qt * 64 + co_l;
      float e00 = epi[co_l * 132 + 2 * q];
      float e01 = epi[co_l * 132 + 2 * q + 1];
      float e10 = epi[co_l * 132 + 64 + 2 * q];
      float e11 = epi[co_l * 132 + 64 + 2 * q + 1];
      float4 vv = make_float4(e00, e10, e01, e11); // ox=4q: (px0,v=2q),(px1,2q),(px0,2q+1),(px1,2q+1)
      *(float4*)&out[((size_t)(n * 256 + co) * 128 + oy) * 128 + 4 * q] = vv;
    }
  }
}

// stats over NCHW buffer, one block per (n,c): 16384 contiguous
__global__ void k_stats_nchw(const float* __restrict__ buf, float* __restrict__ sums) {
  __shared__ float red[256];
  int b = blockIdx.x;
  int c = b & 255;
  int t = threadIdx.x;
  const float* p = buf + (size_t)b * 16384;
  float s = 0.f, q = 0.f;
  for (int i = t; i < 16384; i += 256) {
    float v = p[i];
    s += v; q += v * v;
  }
  red[t] = s; __syncthreads();
  for (int w = 128; w > 0; w >>= 1) { if (t < w) red[t] += red[t + w]; __syncthreads(); }
  float ts = red[0];
  __syncthreads();
  red[t] = q; __syncthreads();
  for (int w = 128; w > 0; w >>= 1) { if (t < w) red[t] += red[t + w]; __syncthreads(); }
  if (t == 0) { atomicAdd(&sums[c], ts); atomicAdd(&sums[256 + c], red[0]); }
}

__global__ void k_norm_nchw(float* __restrict__ buf, const float* __restrict__ scsh) {
  int idx = blockIdx.x * 256 + threadIdx.x; // float4 index
  int c = (idx >> 12) & 255;
  float sc = scsh[c], sh = scsh[256 + c];
  float4 v = *(float4*)&buf[(size_t)idx * 4];
  v.x = fmaxf(fmaf(v.x, sc, sh), 0.f);
  v.y = fmaxf(fmaf(v.y, sc, sh), 0.f);
  v.z = fmaxf(fmaf(v.z, sc, sh), 0.f);
  v.w = fmaxf(fmaf(v.w, sc, sh), 0.f);
  *(float4*)&buf[(size_t)idx * 4] = v;
}

extern "C" void kernel_launch(void* const* d_in, const int* in_sizes, int n_in,
                              void* d_out, int out_size, void* d_ws, size_t ws_size,
                              hipStream_t stream) {
  (void)in_sizes; (void)n_in; (void)out_size; (void)ws_size;
  const float* x      = (const float*)d_in[0];
  const float* w_off  = (const float*)d_in[1];
  const float* b_off  = (const float*)d_in[2];
  const float* w_dcn  = (const float*)d_in[3];
  const float* b_dcn  = (const float*)d_in[4];
  const float* gamma1 = (const float*)d_in[5];
  const float* beta1  = (const float*)d_in[6];
  const float* w_ct   = (const float*)d_in[7];
  const float* gamma2 = (const float*)d_in[8];
  const float* beta2  = (const float*)d_in[9];
  float* ws  = (float*)d_ws;
  float* xt  = ws + OFF_XT;
  float* y1  = ws + OFF_Y1;
  float* om  = ws + OFF_OM;
  float* wd  = ws + OFF_WD;
  unsigned short* wcb = (unsigned short*)(ws + OFF_WC);
  float* st  = ws + OFF_ST;
  unsigned short* y1b = (unsigned short*)(ws + OFF_XT); // reuses xt region after k_dcn
  float* out = (float*)d_out;

  hipMemsetAsync(st, 0, 2048 * sizeof(float), stream);
  k_init_om<<<3456, 256, 0, stream>>>(b_off, om);
  k_transpose_x<<<dim3(512, 8, 2), 256, 0, stream>>>(x, xt);
  k_transpose_wdcn<<<2304, 256, 0, stream>>>(w_dcn, wd);
  k_prep_wct<<<4096, 256, 0, stream>>>(w_ct, wcb);
  k_offset_conv<<<dim3(128, 8), 256, 0, stream>>>(x, w_off, om);
  k_dcn<<<512, 256, 0, stream>>>(xt, om, wd, b_dcn, y1);
  k_stats_cl<<<512, 256, 0, stream>>>(y1, st);
  k_finalize<<<1, 256, 0, stream>>>(st, gamma1, beta1, st + 512, 1.f / 32768.f);
  k_norm_cl<<<8192, 256, 0, stream>>>(y1, st + 512, y1b);
  k_convt_mfma<<<dim3(512, 2), 512, 0, stream>>>(y1b, wcb, out);
  k_stats_nchw<<<2048, 256, 0, stream>>>(out, st + 1024);
  k_finalize<<<1, 256, 0, stream>>>(st + 1024, gamma2, beta2, st + 1536, 1.f / 131072.f);
  k_norm_nchw<<<32768, 256, 0, stream>>>(out, st + 1536);
}

// Round 4
// 731.658 us; speedup vs baseline: 2.4490x; 1.2619x over previous
//
#include <hip/hip_runtime.h>

// Problem constants
// x: (8,256,64,64), w_off:(27,256,3,3), w_dcn:(256,256,3,3), w_ct:(256,256,4,4)
// out: (8,256,128,128) fp32

// ws layout (float offsets)
#define OFF_XT   0u
#define SZ_XT    (8u*64u*64u*256u)          // 8388608  x in NHWC fp32
#define OFF_Y1   (OFF_XT + SZ_XT)           // 8388608  y1 raw/normalized bf16 (8M ushorts)
#define SZ_Y1    SZ_XT
#define OFF_OM   (OFF_Y1 + SZ_Y1)           // 16777216 offset-conv out (8,27,64,64)
#define SZ_OM    (8u*27u*4096u)             // 884736
#define OFF_WD   (OFF_OM + SZ_OM)           // 17661952 wdb bf16 [k][chunk][co][ci32] (589824 ushorts)
#define SZ_WD    (9u*256u*256u)
#define OFF_WC   (OFF_WD + SZ_WD)           // 18251776 wcb bf16 packed
#define SZ_WC    (16u*256u*256u)
#define OFF_ST   (OFF_WC + SZ_WC)           // 19300352 stats: 2048 floats

typedef __attribute__((ext_vector_type(8))) short bf16x8;
typedef __attribute__((ext_vector_type(4))) float f32x4;

__device__ __forceinline__ unsigned short f2bf(float f) {
  unsigned int u = __float_as_uint(f);
  u += 0x7fffu + ((u >> 16) & 1u);
  return (unsigned short)(u >> 16);
}

__global__ void k_init_om(const float* __restrict__ b_off, float* __restrict__ om) {
  int idx = blockIdx.x * 256 + threadIdx.x;
  if (idx < 8 * 27 * 4096) {
    int c = (idx >> 12) % 27;
    om[idx] = b_off[c];
  }
}

// NCHW -> NHWC transpose of x, per (n,y): 256(C) x 64(W) plane
__global__ __launch_bounds__(256) void k_transpose_x(const float* __restrict__ x,
                                                     float* __restrict__ xt) {
  __shared__ float tile[32][33];
  int ny = blockIdx.x;          // n*64 + y
  int n = ny >> 6, y = ny & 63;
  int c0 = blockIdx.y * 32;
  int w0 = blockIdx.z * 32;
  int t = threadIdx.x;
  int tx = t & 31, ty = t >> 5; // ty 0..7
#pragma unroll
  for (int i = 0; i < 4; ++i) {
    int c = c0 + ty + i * 8;
    tile[ty + i * 8][tx] = x[(((n * 256 + c) * 64 + y) << 6) + w0 + tx];
  }
  __syncthreads();
#pragma unroll
  for (int i = 0; i < 4; ++i) {
    int wl = ty + i * 8;
    xt[(((n * 64 + y) * 64 + (w0 + wl)) << 8) + c0 + tx] = tile[tx][wl];
  }
}

// w_dcn -> bf16 packed [k][chunk(8)][co(256)][ci 32]
__global__ void k_prep_wdcn(const float* __restrict__ w, unsigned short* __restrict__ wdb) {
  int idx = blockIdx.x * 256 + threadIdx.x; // < 589824
  if (idx < 589824) {
    int cil = idx & 31;
    int co = (idx >> 5) & 255;
    int chunk = (idx >> 13) & 7;
    int k = idx >> 16;
    int ci = chunk * 32 + cil;
    wdb[idx] = f2bf(w[(co * 256 + ci) * 9 + k]);
  }
}

// w_ct -> bf16 packed [py][px][tap][chunk][co 256][ci 32]
__global__ void k_prep_wct(const float* __restrict__ w, unsigned short* __restrict__ wcb) {
  int idx = blockIdx.x * 256 + threadIdx.x; // < 1048576
  int cil = idx & 31;
  int co = (idx >> 5) & 255;
  int chunk = (idx >> 13) & 7;
  int tap = (idx >> 16) & 3;
  int px = (idx >> 18) & 1;
  int py = (idx >> 19) & 1;
  int ci = chunk * 32 + cil;
  int krA = (py == 0) ? 3 : 2, krB = (py == 0) ? 1 : 0;
  int kc0 = (px == 0) ? 3 : 2, kc1 = kc0 - 2;
  int kr = (tap < 2) ? krA : krB;
  int kc = (tap & 1) ? kc1 : kc0;
  float v = w[(ci << 12) + (co << 4) + kr * 4 + kc];
  wcb[idx] = f2bf(v);
}

// 3x3 conv 256->27, SAME. grid (128, 8): (n*16+tile, ci-chunk of 32). atomicAdd into om.
__global__ __launch_bounds__(256) void k_offset_conv(const float* __restrict__ x,
                                                     const float* __restrict__ w_off,
                                                     float* __restrict__ om) {
  __shared__ float wl[32][9][27];
  __shared__ float xs[8][18 * 19];
  int bx = blockIdx.x;
  int n = bx >> 4;
  int tile = bx & 15;
  int ty0 = (tile >> 2) * 16, tx0 = (tile & 3) * 16;
  int ci0 = blockIdx.y * 32;
  int t = threadIdx.x;
  for (int i = t; i < 32 * 9 * 27; i += 256) {
    int ci = i / 243, r = i % 243, tap = r / 27, co = r % 27;
    wl[ci][tap][co] = w_off[(co * 256 + ci0 + ci) * 9 + tap];
  }
  float acc[27];
#pragma unroll
  for (int co = 0; co < 27; ++co) acc[co] = 0.f;
  int tx = t & 15, ty = t >> 4;
  for (int cig = 0; cig < 4; ++cig) {
    __syncthreads();
    for (int i = t; i < 8 * 324; i += 256) {
      int cc = i / 324, r2 = i % 324;
      int rr = r2 / 18, colc = r2 % 18;
      int yy = ty0 + rr - 1, xx = tx0 + colc - 1;
      float v = 0.f;
      if (yy >= 0 && yy < 64 && xx >= 0 && xx < 64)
        v = x[(((n * 256 + ci0 + cig * 8 + cc) * 64 + yy) << 6) + xx];
      xs[cc][rr * 19 + colc] = v;
    }
    __syncthreads();
    for (int cc = 0; cc < 8; ++cc) {
      int cil = cig * 8 + cc;
#pragma unroll
      for (int ky = 0; ky < 3; ++ky)
#pragma unroll
        for (int kx = 0; kx < 3; ++kx) {
          float v = xs[cc][(ty + ky) * 19 + tx + kx];
          int tap = ky * 3 + kx;
#pragma unroll
          for (int co = 0; co < 27; ++co) acc[co] += v * wl[cil][tap][co];
        }
    }
  }
  int yy = ty0 + ty, xx = tx0 + tx;
#pragma unroll
  for (int co = 0; co < 27; ++co)
    atomicAdd(&om[(n * 27 + co) * 4096 + (yy << 6) + xx], acc[co]);
}

// DCN v2 via bf16 MFMA. grid 512 (n*64+y), 512 threads (8 waves).
// Wave: mh = wave>>2 (pos half of 32), ns = wave&3 (co slice of 64).
// Output: y1r raw bf16 NHWC + fused BN1 stats (fp32, pre-rounding) into st.
__global__ __launch_bounds__(512) void k_dcn_mfma(const float* __restrict__ xt,
                                                  const float* __restrict__ om,
                                                  const unsigned short* __restrict__ wdb,
                                                  const float* __restrict__ b_dcn,
                                                  unsigned short* __restrict__ y1r,
                                                  float* __restrict__ st) {
  __shared__ unsigned short aLds[64 * 40];   // [pos][32ci + 8 pad]
  __shared__ unsigned short wLds[256 * 40];  // [co][32ci + 8 pad]
  __shared__ int p_y0[64], p_y1[64], p_x0[64], p_x1[64];
  __shared__ float p_w[64][4];
  int bid = blockIdx.x;
  int n = bid >> 6, y = bid & 63;
  int t = threadIdx.x;
  int wave = t >> 6, lane = t & 63;
  int mh = wave >> 2, ns = wave & 3;
  int l15 = lane & 15, l4 = lane >> 4;
  int p = t >> 3, slot = t & 7; // staging roles: pos p, ci quad slot*4
  f32x4 acc[2][4] = {};

  for (int tap = 0; tap < 9; ++tap) {
    int ki = tap / 3, kj = tap % 3;
    __syncthreads(); // prev tap's LDS reads + p_* reads done
    if (t < 64) {
      int pp = t;
      const float* omn = om + (n * 27) * 4096 + (y << 6) + pp;
      float offy = omn[(2 * tap) * 4096];
      float offx = omn[(2 * tap + 1) * 4096];
      float mv = omn[(18 + tap) * 4096];
      float mask = 1.f / (1.f + expf(-mv));
      float ysf = (float)(y + ki - 1) + offy;
      float xsf = (float)(pp + kj - 1) + offx;
      float y0f = floorf(ysf), x0f = floorf(xsf);
      float dy = ysf - y0f, dx = xsf - x0f;
      int y0 = (int)y0f, x0 = (int)x0f;
      int y1c = y0 + 1, x1c = x0 + 1;
      float v00 = (y0 >= 0 && y0 < 64 && x0 >= 0 && x0 < 64) ? 1.f : 0.f;
      float v01 = (y0 >= 0 && y0 < 64 && x1c >= 0 && x1c < 64) ? 1.f : 0.f;
      float v10 = (y1c >= 0 && y1c < 64 && x0 >= 0 && x0 < 64) ? 1.f : 0.f;
      float v11 = (y1c >= 0 && y1c < 64 && x1c >= 0 && x1c < 64) ? 1.f : 0.f;
      p_y0[pp] = min(max(y0, 0), 63);
      p_y1[pp] = min(max(y1c, 0), 63);
      p_x0[pp] = min(max(x0, 0), 63);
      p_x1[pp] = min(max(x1c, 0), 63);
      p_w[pp][0] = (1.f - dy) * (1.f - dx) * mask * v00;
      p_w[pp][1] = (1.f - dy) * dx * mask * v01;
      p_w[pp][2] = dy * (1.f - dx) * mask * v10;
      p_w[pp][3] = dy * dx * mask * v11;
    }
    __syncthreads(); // p_* ready
    int y0 = p_y0[p], y1c = p_y1[p], x0 = p_x0[p], x1c = p_x1[p];
    float w0 = p_w[p][0], w1 = p_w[p][1], w2 = p_w[p][2], w3 = p_w[p][3];
    int nb = n << 12;
    const float* a00 = xt + ((size_t)(nb + (y0 << 6) + x0) << 8) + slot * 4;
    const float* a01 = xt + ((size_t)(nb + (y0 << 6) + x1c) << 8) + slot * 4;
    const float* a10 = xt + ((size_t)(nb + (y1c << 6) + x0) << 8) + slot * 4;
    const float* a11 = xt + ((size_t)(nb + (y1c << 6) + x1c) << 8) + slot * 4;
    const unsigned short* wsrc = wdb + (size_t)tap * 65536;
    for (int chunk = 0; chunk < 8; ++chunk) {
      if (chunk) __syncthreads(); // prev chunk's MFMA LDS reads done
      // stage W: 256co x 32ci bf16, linear
      {
        const unsigned short* wp = wsrc + chunk * 8192;
#pragma unroll
        for (int it = 0; it < 2; ++it) {
          int task = it * 512 + t;
          int co = task >> 2, sl = task & 3;
          *(uint4*)&wLds[co * 40 + sl * 8] = *(const uint4*)&wp[co * 32 + sl * 8];
        }
      }
      // stage A: gather + lerp + bf16
      {
        int cioff = chunk * 32;
        float4 c00 = *(const float4*)(a00 + cioff);
        float4 c01 = *(const float4*)(a01 + cioff);
        float4 c10 = *(const float4*)(a10 + cioff);
        float4 c11 = *(const float4*)(a11 + cioff);
        float v0 = w0 * c00.x + w1 * c01.x + w2 * c10.x + w3 * c11.x;
        float v1 = w0 * c00.y + w1 * c01.y + w2 * c10.y + w3 * c11.y;
        float v2 = w0 * c00.z + w1 * c01.z + w2 * c10.z + w3 * c11.z;
        float v3 = w0 * c00.w + w1 * c01.w + w2 * c10.w + w3 * c11.w;
        uint2 pk;
        pk.x = (unsigned int)f2bf(v0) | ((unsigned int)f2bf(v1) << 16);
        pk.y = (unsigned int)f2bf(v2) | ((unsigned int)f2bf(v3) << 16);
        *(uint2*)&aLds[p * 40 + slot * 4] = pk;
      }
      __syncthreads();
      bf16x8 b[4], a[2];
#pragma unroll
      for (int j = 0; j < 4; ++j)
        b[j] = *(bf16x8*)&wLds[(ns * 64 + 16 * j + l15) * 40 + l4 * 8];
#pragma unroll
      for (int i = 0; i < 2; ++i)
        a[i] = *(bf16x8*)&aLds[(mh * 32 + 16 * i + l15) * 40 + l4 * 8];
#pragma unroll
      for (int i = 0; i < 2; ++i)
#pragma unroll
        for (int j = 0; j < 4; ++j)
          acc[i][j] = __builtin_amdgcn_mfma_f32_16x16x32_bf16(a[i], b[j], acc[i][j], 0, 0, 0);
    }
  }
  // epilogue: bias, bf16 store (NHWC), fused stats
  unsigned short* dstbase = y1r + ((size_t)(n * 4096 + y * 64) << 8);
#pragma unroll
  for (int j = 0; j < 4; ++j) {
    int co = ns * 64 + 16 * j + l15;
    float bias = b_dcn[co];
    float ss = 0.f, qq = 0.f;
#pragma unroll
    for (int i = 0; i < 2; ++i) {
#pragma unroll
      for (int r = 0; r < 4; ++r) {
        float v = acc[i][j][r] + bias;
        int pos = mh * 32 + 16 * i + l4 * 4 + r;
        dstbase[pos * 256 + co] = f2bf(v);
        ss += v; qq += v * v;
      }
    }
    ss += __shfl_xor(ss, 16); ss += __shfl_xor(ss, 32);
    qq += __shfl_xor(qq, 16); qq += __shfl_xor(qq, 32);
    if (l4 == 0) { atomicAdd(&st[co], ss); atomicAdd(&st[256 + co], qq); }
  }
}

__global__ void k_finalize(const float* __restrict__ sums, const float* __restrict__ gamma,
                           const float* __restrict__ beta, float* __restrict__ scsh,
                           float inv_cnt) {
  int t = threadIdx.x;
  float mu = sums[t] * inv_cnt;
  float var = sums[256 + t] * inv_cnt - mu * mu;
  float r = rsqrtf(var + 1e-5f);
  float sc = gamma[t] * r;
  scsh[t] = sc;
  scsh[256 + t] = beta[t] - mu * sc;
}

// normalize+relu in place on bf16 NHWC buffer
__global__ void k_norm_b16(unsigned short* __restrict__ y1r, const float* __restrict__ scsh) {
  int idx = blockIdx.x * 256 + threadIdx.x; // uint4 index (8 bf16)
  int cb = (idx & 31) * 8;
  uint4 v = *(uint4*)&y1r[(size_t)idx * 8];
  float4 sc0 = *(const float4*)&scsh[cb];
  float4 sc1 = *(const float4*)&scsh[cb + 4];
  float4 sh0 = *(const float4*)&scsh[256 + cb];
  float4 sh1 = *(const float4*)&scsh[256 + cb + 4];
  float f0 = __uint_as_float(v.x << 16), f1 = __uint_as_float(v.x & 0xffff0000u);
  float f2 = __uint_as_float(v.y << 16), f3 = __uint_as_float(v.y & 0xffff0000u);
  float f4 = __uint_as_float(v.z << 16), f5 = __uint_as_float(v.z & 0xffff0000u);
  float f6 = __uint_as_float(v.w << 16), f7 = __uint_as_float(v.w & 0xffff0000u);
  f0 = fmaxf(fmaf(f0, sc0.x, sh0.x), 0.f); f1 = fmaxf(fmaf(f1, sc0.y, sh0.y), 0.f);
  f2 = fmaxf(fmaf(f2, sc0.z, sh0.z), 0.f); f3 = fmaxf(fmaf(f3, sc0.w, sh0.w), 0.f);
  f4 = fmaxf(fmaf(f4, sc1.x, sh1.x), 0.f); f5 = fmaxf(fmaf(f5, sc1.y, sh1.y), 0.f);
  f6 = fmaxf(fmaf(f6, sc1.z, sh1.z), 0.f); f7 = fmaxf(fmaf(f7, sc1.w, sh1.w), 0.f);
  uint4 o;
  o.x = (unsigned int)f2bf(f0) | ((unsigned int)f2bf(f1) << 16);
  o.y = (unsigned int)f2bf(f2) | ((unsigned int)f2bf(f3) << 16);
  o.z = (unsigned int)f2bf(f4) | ((unsigned int)f2bf(f5) << 16);
  o.w = (unsigned int)f2bf(f6) | ((unsigned int)f2bf(f7) << 16);
  *(uint4*)&y1r[(size_t)idx * 8] = o;
}

// ConvTranspose 4x4 s2 p1 via bf16 MFMA + fused BN2 stats. grid (512, 2): (n*64+u, py).
__global__ __launch_bounds__(512) void k_convt_mfma(const unsigned short* __restrict__ y1b,
                                                    const unsigned short* __restrict__ wcb,
                                                    float* __restrict__ out,
                                                    float* __restrict__ st2) {
  __shared__ unsigned short sh[2 * 66 * 40 + 2 * 256 * 40]; // 51520 B
  unsigned short* aLds = sh;
  unsigned short* wLds = sh + 2 * 66 * 40;

  int bx = blockIdx.x;
  int n = bx >> 6, u = bx & 63;
  int py = blockIdx.y;
  int t = threadIdx.x;
  int wave = t >> 6, lane = t & 63;
  int px_w = wave >> 2, ns = wave & 3;
  int co_base = ns * 64;
  int l15 = lane & 15, l4 = lane >> 4;
  int iy[2];
  iy[0] = (py == 0) ? u - 1 : u;
  iy[1] = (py == 0) ? u : u + 1;
  bool rv[2] = {iy[0] >= 0 && iy[0] < 64, iy[1] >= 0 && iy[1] < 64};

  f32x4 acc[4][4] = {};

  for (int chunk = 0; chunk < 8; ++chunk) {
    int ci0 = chunk * 32;
    __syncthreads();
    for (int task = t; task < 528; task += 512) {
      int slot = task & 3;
      int c = (task >> 2) % 66;
      int r = task / 264;
      int ix = c - 1;
      uint4 val = make_uint4(0u, 0u, 0u, 0u);
      if (rv[r] && ix >= 0 && ix < 64)
        val = *(const uint4*)&y1b[((size_t)(n * 4096 + iy[r] * 64 + ix) * 256 + ci0 + slot * 8)];
      *(uint4*)&aLds[(r * 66 + c) * 40 + slot * 8] = val;
    }
    for (int tap = 0; tap < 4; ++tap) {
      __syncthreads();
#pragma unroll
      for (int it = 0; it < 4; ++it) {
        int task = it * 512 + t;
        int slot = task & 3;
        int co = (task >> 2) & 255;
        int px = task >> 10;
        const unsigned short* src =
            wcb + ((size_t)((((py * 2 + px) * 4 + tap) * 8 + chunk) * 256 + co) * 32 + slot * 8);
        uint4 val = *(const uint4*)src;
        *(uint4*)&wLds[(px * 256 + co) * 40 + slot * 8] = val;
      }
      __syncthreads();
      int r = tap >> 1, s = tap & 1;
      bf16x8 b[4];
#pragma unroll
      for (int j = 0; j < 4; ++j)
        b[j] = *(bf16x8*)&wLds[(px_w * 256 + co_base + 16 * j + l15) * 40 + l4 * 8];
#pragma unroll
      for (int i = 0; i < 4; ++i) {
        int c = 16 * i + l15 + s + px_w;
        bf16x8 a = *(bf16x8*)&aLds[(r * 66 + c) * 40 + l4 * 8];
#pragma unroll
        for (int j = 0; j < 4; ++j)
          acc[i][j] = __builtin_amdgcn_mfma_f32_16x16x32_bf16(a, b[j], acc[i][j], 0, 0, 0);
      }
    }
  }

  // epilogue: interleave px via LDS, write contiguous 128-float rows, fused BN2 stats.
  float* epi = (float*)sh;
  int oy = 2 * u + py;
  for (int qt = 0; qt < 4; ++qt) {
    __syncthreads();
    if (ns == qt) {
#pragma unroll
      for (int i = 0; i < 4; ++i)
#pragma unroll
        for (int j = 0; j < 4; ++j) {
          int co_l = 16 * j + l15;
          int vbase = 16 * i + l4 * 4;
          *(f32x4*)&epi[co_l * 132 + px_w * 64 + vbase] = acc[i][j];
        }
    }
    __syncthreads();
#pragma unroll
    for (int it = 0; it < 4; ++it) {
      int task = it * 512 + t;
      int q = task & 31;
      int co_l = task >> 5;
      int co = qt * 64 + co_l;
      float e00 = epi[co_l * 132 + 2 * q];
      float e01 = epi[co_l * 132 + 2 * q + 1];
      float e10 = epi[co_l * 132 + 64 + 2 * q];
      float e11 = epi[co_l * 132 + 64 + 2 * q + 1];
      float4 vv = make_float4(e00, e10, e01, e11);
      *(float4*)&out[((size_t)(n * 256 + co) * 128 + oy) * 128 + 4 * q] = vv;
      float ss = e00 + e01 + e10 + e11;
      float qq = e00 * e00 + e01 * e01 + e10 * e10 + e11 * e11;
      ss += __shfl_xor(ss, 1); qq += __shfl_xor(qq, 1);
      ss += __shfl_xor(ss, 2); qq += __shfl_xor(qq, 2);
      ss += __shfl_xor(ss, 4); qq += __shfl_xor(qq, 4);
      ss += __shfl_xor(ss, 8); qq += __shfl_xor(qq, 8);
      ss += __shfl_xor(ss, 16); qq += __shfl_xor(qq, 16);
      if ((t & 31) == 0) { atomicAdd(&st2[co], ss); atomicAdd(&st2[256 + co], qq); }
    }
  }
}

__global__ void k_norm_nchw(float* __restrict__ buf, const float* __restrict__ scsh) {
  int idx = blockIdx.x * 256 + threadIdx.x; // float4 index
  int c = (idx >> 12) & 255;
  float sc = scsh[c], sh = scsh[256 + c];
  float4 v = *(float4*)&buf[(size_t)idx * 4];
  v.x = fmaxf(fmaf(v.x, sc, sh), 0.f);
  v.y = fmaxf(fmaf(v.y, sc, sh), 0.f);
  v.z = fmaxf(fmaf(v.z, sc, sh), 0.f);
  v.w = fmaxf(fmaf(v.w, sc, sh), 0.f);
  *(float4*)&buf[(size_t)idx * 4] = v;
}

extern "C" void kernel_launch(void* const* d_in, const int* in_sizes, int n_in,
                              void* d_out, int out_size, void* d_ws, size_t ws_size,
                              hipStream_t stream) {
  (void)in_sizes; (void)n_in; (void)out_size; (void)ws_size;
  const float* x      = (const float*)d_in[0];
  const float* w_off  = (const float*)d_in[1];
  const float* b_off  = (const float*)d_in[2];
  const float* w_dcn  = (const float*)d_in[3];
  const float* b_dcn  = (const float*)d_in[4];
  const float* gamma1 = (const float*)d_in[5];
  const float* beta1  = (const float*)d_in[6];
  const float* w_ct   = (const float*)d_in[7];
  const float* gamma2 = (const float*)d_in[8];
  const float* beta2  = (const float*)d_in[9];
  float* ws  = (float*)d_ws;
  float* xt  = ws + OFF_XT;
  unsigned short* y1r = (unsigned short*)(ws + OFF_Y1);
  float* om  = ws + OFF_OM;
  unsigned short* wdb = (unsigned short*)(ws + OFF_WD);
  unsigned short* wcb = (unsigned short*)(ws + OFF_WC);
  float* st  = ws + OFF_ST;
  float* out = (float*)d_out;

  hipMemsetAsync(st, 0, 2048 * sizeof(float), stream);
  k_init_om<<<3456, 256, 0, stream>>>(b_off, om);
  k_transpose_x<<<dim3(512, 8, 2), 256, 0, stream>>>(x, xt);
  k_prep_wdcn<<<2304, 256, 0, stream>>>(w_dcn, wdb);
  k_prep_wct<<<4096, 256, 0, stream>>>(w_ct, wcb);
  k_offset_conv<<<dim3(128, 8), 256, 0, stream>>>(x, w_off, om);
  k_dcn_mfma<<<512, 512, 0, stream>>>(xt, om, wdb, b_dcn, y1r, st);
  k_finalize<<<1, 256, 0, stream>>>(st, gamma1, beta1, st + 512, 1.f / 32768.f);
  k_norm_b16<<<4096, 256, 0, stream>>>(y1r, st + 512);
  k_convt_mfma<<<dim3(512, 2), 512, 0, stream>>>(y1r, wcb, out, st + 1024);
  k_finalize<<<1, 256, 0, stream>>>(st + 1024, gamma2, beta2, st + 1536, 1.f / 131072.f);
  k_norm_nchw<<<32768, 256, 0, stream>>>(out, st + 1536);
}

// Round 5
// 533.583 us; speedup vs baseline: 3.3582x; 1.3712x over previous
//
#include <hip/hip_runtime.h>

// Problem constants
// x: (8,256,64,64), w_off:(27,256,3,3), w_dcn:(256,256,3,3), w_ct:(256,256,4,4)
// out: (8,256,128,128) fp32

// ws layout (float offsets)
#define OFF_XT   0u
#define SZ_XT    (8u*64u*64u*256u)          // xtb bf16 NHWC (8.4M ushorts in 33.5MB slot)
#define OFF_Y1   (OFF_XT + SZ_XT)           // y1 raw/normalized bf16 NHWC
#define SZ_Y1    SZ_XT
#define OFF_OM   (OFF_Y1 + SZ_Y1)           // offset-conv out (8,27,64,64)
#define SZ_OM    (8u*27u*4096u)
#define OFF_WD   (OFF_OM + SZ_OM)           // wdb bf16 [k][chunk][co][ci32]
#define SZ_WD    (9u*256u*256u)
#define OFF_WC   (OFF_WD + SZ_WD)           // wcb bf16 packed [py][px][tap][chunk][co][ci32]
#define SZ_WC    (16u*256u*256u)
#define OFF_ST   (OFF_WC + SZ_WC)           // stats: 2048 floats

typedef __attribute__((ext_vector_type(8))) short bf16x8;
typedef __attribute__((ext_vector_type(4))) float f32x4;

__device__ __forceinline__ unsigned short f2bf(float f) {
  unsigned int u = __float_as_uint(f);
  u += 0x7fffu + ((u >> 16) & 1u);
  return (unsigned short)(u >> 16);
}

__device__ __forceinline__ unsigned int lerp_pair(unsigned int u00, unsigned int u01,
                                                  unsigned int u10, unsigned int u11,
                                                  float w0, float w1, float w2, float w3) {
  float lo = w0 * __uint_as_float(u00 << 16) + w1 * __uint_as_float(u01 << 16) +
             w2 * __uint_as_float(u10 << 16) + w3 * __uint_as_float(u11 << 16);
  float hi = w0 * __uint_as_float(u00 & 0xffff0000u) + w1 * __uint_as_float(u01 & 0xffff0000u) +
             w2 * __uint_as_float(u10 & 0xffff0000u) + w3 * __uint_as_float(u11 & 0xffff0000u);
  return (unsigned int)f2bf(lo) | ((unsigned int)f2bf(hi) << 16);
}

__global__ void k_init_om(const float* __restrict__ b_off, float* __restrict__ om) {
  int idx = blockIdx.x * 256 + threadIdx.x;
  if (idx < 8 * 27 * 4096) {
    int c = (idx >> 12) % 27;
    om[idx] = b_off[c];
  }
}

// NCHW -> NHWC bf16 transpose of x
__global__ __launch_bounds__(256) void k_transpose_x(const float* __restrict__ x,
                                                     unsigned short* __restrict__ xtb) {
  __shared__ float tile[32][33];
  int ny = blockIdx.x;          // n*64 + y
  int n = ny >> 6, y = ny & 63;
  int c0 = blockIdx.y * 32;
  int w0 = blockIdx.z * 32;
  int t = threadIdx.x;
  int tx = t & 31, ty = t >> 5; // ty 0..7
#pragma unroll
  for (int i = 0; i < 4; ++i) {
    int c = c0 + ty + i * 8;
    tile[ty + i * 8][tx] = x[(((n * 256 + c) * 64 + y) << 6) + w0 + tx];
  }
  __syncthreads();
#pragma unroll
  for (int i = 0; i < 4; ++i) {
    int wl = ty + i * 8;
    xtb[(((n * 64 + y) * 64 + (w0 + wl)) << 8) + c0 + tx] = f2bf(tile[tx][wl]);
  }
}

// w_dcn -> bf16 packed [k][chunk(8)][co(256)][ci 32]
__global__ void k_prep_wdcn(const float* __restrict__ w, unsigned short* __restrict__ wdb) {
  int idx = blockIdx.x * 256 + threadIdx.x;
  if (idx < 589824) {
    int cil = idx & 31;
    int co = (idx >> 5) & 255;
    int chunk = (idx >> 13) & 7;
    int k = idx >> 16;
    int ci = chunk * 32 + cil;
    wdb[idx] = f2bf(w[(co * 256 + ci) * 9 + k]);
  }
}

// w_ct -> bf16 packed [py][px][tap][chunk][co 256][ci 32]
__global__ void k_prep_wct(const float* __restrict__ w, unsigned short* __restrict__ wcb) {
  int idx = blockIdx.x * 256 + threadIdx.x;
  int cil = idx & 31;
  int co = (idx >> 5) & 255;
  int chunk = (idx >> 13) & 7;
  int tap = (idx >> 16) & 3;
  int px = (idx >> 18) & 1;
  int py = (idx >> 19) & 1;
  int ci = chunk * 32 + cil;
  int krA = (py == 0) ? 3 : 2, krB = (py == 0) ? 1 : 0;
  int kc0 = (px == 0) ? 3 : 2, kc1 = kc0 - 2;
  int kr = (tap < 2) ? krA : krB;
  int kc = (tap & 1) ? kc1 : kc0;
  float v = w[(ci << 12) + (co << 4) + kr * 4 + kc];
  wcb[idx] = f2bf(v);
}

// 3x3 conv 256->27, SAME. grid (128, 8). atomicAdd into om.
__global__ __launch_bounds__(256) void k_offset_conv(const float* __restrict__ x,
                                                     const float* __restrict__ w_off,
                                                     float* __restrict__ om) {
  __shared__ float wl[32][9][27];
  __shared__ float xs[8][18 * 19];
  int bx = blockIdx.x;
  int n = bx >> 4;
  int tile = bx & 15;
  int ty0 = (tile >> 2) * 16, tx0 = (tile & 3) * 16;
  int ci0 = blockIdx.y * 32;
  int t = threadIdx.x;
  for (int i = t; i < 32 * 9 * 27; i += 256) {
    int ci = i / 243, r = i % 243, tap = r / 27, co = r % 27;
    wl[ci][tap][co] = w_off[(co * 256 + ci0 + ci) * 9 + tap];
  }
  float acc[27];
#pragma unroll
  for (int co = 0; co < 27; ++co) acc[co] = 0.f;
  int tx = t & 15, ty = t >> 4;
  for (int cig = 0; cig < 4; ++cig) {
    __syncthreads();
    for (int i = t; i < 8 * 324; i += 256) {
      int cc = i / 324, r2 = i % 324;
      int rr = r2 / 18, colc = r2 % 18;
      int yy = ty0 + rr - 1, xx = tx0 + colc - 1;
      float v = 0.f;
      if (yy >= 0 && yy < 64 && xx >= 0 && xx < 64)
        v = x[(((n * 256 + ci0 + cig * 8 + cc) * 64 + yy) << 6) + xx];
      xs[cc][rr * 19 + colc] = v;
    }
    __syncthreads();
    for (int cc = 0; cc < 8; ++cc) {
      int cil = cig * 8 + cc;
#pragma unroll
      for (int ky = 0; ky < 3; ++ky)
#pragma unroll
        for (int kx = 0; kx < 3; ++kx) {
          float v = xs[cc][(ty + ky) * 19 + tx + kx];
          int tap = ky * 3 + kx;
#pragma unroll
          for (int co = 0; co < 27; ++co) acc[co] += v * wl[cil][tap][co];
        }
    }
  }
  int yy = ty0 + ty, xx = tx0 + tx;
#pragma unroll
  for (int co = 0; co < 27; ++co)
    atomicAdd(&om[(n * 27 + co) * 4096 + (yy << 6) + xx], acc[co]);
}

// DCN v2 via bf16 MFMA, y-pair blocks. grid 256: bid&7 = n (XCD affinity), bid>>3 = ypair.
// 512 threads, 8 waves: mh = wave>>2 (pos half of 64), ns = wave&3 (co slice 64).
__global__ __launch_bounds__(512) void k_dcn2(const unsigned short* __restrict__ xtb,
                                              const float* __restrict__ om,
                                              const unsigned short* __restrict__ wdb,
                                              const float* __restrict__ b_dcn,
                                              unsigned short* __restrict__ y1r) {
  __shared__ unsigned short aLds[128 * 40];  // [pos][32ci + 8 pad]
  __shared__ unsigned short wLds[256 * 40];  // [co][32ci + 8 pad]
  __shared__ int p_y0[128], p_y1[128], p_x0[128], p_x1[128];
  __shared__ float p_w[128][4];
  int bid = blockIdx.x;
  int n = bid & 7, yp = bid >> 3;
  int ybase = yp * 2;
  int t = threadIdx.x;
  int wave = t >> 6, lane = t & 63;
  int mh = wave >> 2, ns = wave & 3;
  int l15 = lane & 15, l4 = lane >> 4;
  int gp = t >> 2, gq = t & 3; // gather roles: pos, ci-oct
  f32x4 acc[4][4] = {};

  for (int tap = 0; tap < 9; ++tap) {
    int ki = tap / 3, kj = tap % 3;
    __syncthreads(); // prev tap LDS reads + p_* reads done
    if (t < 128) {
      int pp = t;
      int yy = ybase + (pp >> 6), xx = pp & 63;
      const float* base = om + (n * 27) * 4096 + (yy << 6) + xx;
      float offy = base[(2 * tap) * 4096];
      float offx = base[(2 * tap + 1) * 4096];
      float mv = base[(18 + tap) * 4096];
      float mask = 1.f / (1.f + expf(-mv));
      float ysf = (float)(yy + ki - 1) + offy;
      float xsf = (float)(xx + kj - 1) + offx;
      float y0f = floorf(ysf), x0f = floorf(xsf);
      float dy = ysf - y0f, dx = xsf - x0f;
      int y0 = (int)y0f, x0 = (int)x0f;
      int y1c = y0 + 1, x1c = x0 + 1;
      float v00 = (y0 >= 0 && y0 < 64 && x0 >= 0 && x0 < 64) ? 1.f : 0.f;
      float v01 = (y0 >= 0 && y0 < 64 && x1c >= 0 && x1c < 64) ? 1.f : 0.f;
      float v10 = (y1c >= 0 && y1c < 64 && x0 >= 0 && x0 < 64) ? 1.f : 0.f;
      float v11 = (y1c >= 0 && y1c < 64 && x1c >= 0 && x1c < 64) ? 1.f : 0.f;
      p_y0[pp] = min(max(y0, 0), 63);
      p_y1[pp] = min(max(y1c, 0), 63);
      p_x0[pp] = min(max(x0, 0), 63);
      p_x1[pp] = min(max(x1c, 0), 63);
      p_w[pp][0] = (1.f - dy) * (1.f - dx) * mask * v00;
      p_w[pp][1] = (1.f - dy) * dx * mask * v01;
      p_w[pp][2] = dy * (1.f - dx) * mask * v10;
      p_w[pp][3] = dy * dx * mask * v11;
    }
    __syncthreads(); // p_* ready
    int y0 = p_y0[gp], y1c = p_y1[gp], x0 = p_x0[gp], x1c = p_x1[gp];
    float w0 = p_w[gp][0], w1 = p_w[gp][1], w2 = p_w[gp][2], w3 = p_w[gp][3];
    int nb = n << 12;
    const unsigned short* b00 = xtb + ((size_t)(nb + (y0 << 6) + x0) << 8) + gq * 8;
    const unsigned short* b01 = xtb + ((size_t)(nb + (y0 << 6) + x1c) << 8) + gq * 8;
    const unsigned short* b10 = xtb + ((size_t)(nb + (y1c << 6) + x0) << 8) + gq * 8;
    const unsigned short* b11 = xtb + ((size_t)(nb + (y1c << 6) + x1c) << 8) + gq * 8;
    const unsigned short* wsrc = wdb + (size_t)tap * 65536;
    for (int chunk = 0; chunk < 8; ++chunk) {
      if (chunk) __syncthreads(); // prev chunk MFMA reads done
      // stage W: 256co x 32ci
      {
        const unsigned short* wp = wsrc + chunk * 8192;
#pragma unroll
        for (int it = 0; it < 2; ++it) {
          int task = it * 512 + t;
          int co = task >> 2, sl = task & 3;
          *(uint4*)&wLds[co * 40 + sl * 8] = *(const uint4*)&wp[co * 32 + sl * 8];
        }
      }
      // gather A: 128 pos x 32 ci (8 per thread), bf16 corners
      {
        int cio = chunk * 32;
        uint4 c00 = *(const uint4*)(b00 + cio);
        uint4 c01 = *(const uint4*)(b01 + cio);
        uint4 c10 = *(const uint4*)(b10 + cio);
        uint4 c11 = *(const uint4*)(b11 + cio);
        uint4 o;
        o.x = lerp_pair(c00.x, c01.x, c10.x, c11.x, w0, w1, w2, w3);
        o.y = lerp_pair(c00.y, c01.y, c10.y, c11.y, w0, w1, w2, w3);
        o.z = lerp_pair(c00.z, c01.z, c10.z, c11.z, w0, w1, w2, w3);
        o.w = lerp_pair(c00.w, c01.w, c10.w, c11.w, w0, w1, w2, w3);
        *(uint4*)&aLds[gp * 40 + gq * 8] = o;
      }
      __syncthreads();
      bf16x8 b[4], a[4];
#pragma unroll
      for (int j = 0; j < 4; ++j)
        b[j] = *(bf16x8*)&wLds[(ns * 64 + 16 * j + l15) * 40 + l4 * 8];
#pragma unroll
      for (int i = 0; i < 4; ++i)
        a[i] = *(bf16x8*)&aLds[(mh * 64 + 16 * i + l15) * 40 + l4 * 8];
#pragma unroll
      for (int i = 0; i < 4; ++i)
#pragma unroll
        for (int j = 0; j < 4; ++j)
          acc[i][j] = __builtin_amdgcn_mfma_f32_16x16x32_bf16(a[i], b[j], acc[i][j], 0, 0, 0);
    }
  }
  // epilogue: bias + bf16 store (NHWC)
  unsigned short* dst = y1r + ((size_t)(n * 4096 + ybase * 64) << 8);
#pragma unroll
  for (int j = 0; j < 4; ++j) {
    int co = ns * 64 + 16 * j + l15;
    float bias = b_dcn[co];
#pragma unroll
    for (int i = 0; i < 4; ++i)
#pragma unroll
      for (int rr = 0; rr < 4; ++rr) {
        int pos = mh * 64 + 16 * i + l4 * 4 + rr;
        dst[pos * 256 + co] = f2bf(acc[i][j][rr] + bias);
      }
  }
}

// BN1 stats over bf16 NHWC buffer: 256 blocks x 128 rows; thread t owns co=t.
__global__ __launch_bounds__(256) void k_stats_b16(const unsigned short* __restrict__ y1r,
                                                   float* __restrict__ sums) {
  int t = threadIdx.x;
  int r0 = blockIdx.x * 128;
  float s = 0.f, q = 0.f;
  const unsigned short* p = y1r + (size_t)r0 * 256 + t;
  for (int r = 0; r < 128; ++r) {
    float v = __uint_as_float(((unsigned int)p[r * 256]) << 16);
    s += v; q += v * v;
  }
  atomicAdd(&sums[t], s);
  atomicAdd(&sums[256 + t], q);
}

__global__ void k_finalize(const float* __restrict__ sums, const float* __restrict__ gamma,
                           const float* __restrict__ beta, float* __restrict__ scsh,
                           float inv_cnt) {
  int t = threadIdx.x;
  float mu = sums[t] * inv_cnt;
  float var = sums[256 + t] * inv_cnt - mu * mu;
  float r = rsqrtf(var + 1e-5f);
  float sc = gamma[t] * r;
  scsh[t] = sc;
  scsh[256 + t] = beta[t] - mu * sc;
}

// normalize+relu in place on bf16 NHWC buffer
__global__ void k_norm_b16(unsigned short* __restrict__ y1r, const float* __restrict__ scsh) {
  int idx = blockIdx.x * 256 + threadIdx.x; // uint4 index (8 bf16)
  int cb = (idx & 31) * 8;
  uint4 v = *(uint4*)&y1r[(size_t)idx * 8];
  float4 sc0 = *(const float4*)&scsh[cb];
  float4 sc1 = *(const float4*)&scsh[cb + 4];
  float4 sh0 = *(const float4*)&scsh[256 + cb];
  float4 sh1 = *(const float4*)&scsh[256 + cb + 4];
  float f0 = __uint_as_float(v.x << 16), f1 = __uint_as_float(v.x & 0xffff0000u);
  float f2 = __uint_as_float(v.y << 16), f3 = __uint_as_float(v.y & 0xffff0000u);
  float f4 = __uint_as_float(v.z << 16), f5 = __uint_as_float(v.z & 0xffff0000u);
  float f6 = __uint_as_float(v.w << 16), f7 = __uint_as_float(v.w & 0xffff0000u);
  f0 = fmaxf(fmaf(f0, sc0.x, sh0.x), 0.f); f1 = fmaxf(fmaf(f1, sc0.y, sh0.y), 0.f);
  f2 = fmaxf(fmaf(f2, sc0.z, sh0.z), 0.f); f3 = fmaxf(fmaf(f3, sc0.w, sh0.w), 0.f);
  f4 = fmaxf(fmaf(f4, sc1.x, sh1.x), 0.f); f5 = fmaxf(fmaf(f5, sc1.y, sh1.y), 0.f);
  f6 = fmaxf(fmaf(f6, sc1.z, sh1.z), 0.f); f7 = fmaxf(fmaf(f7, sc1.w, sh1.w), 0.f);
  uint4 o;
  o.x = (unsigned int)f2bf(f0) | ((unsigned int)f2bf(f1) << 16);
  o.y = (unsigned int)f2bf(f2) | ((unsigned int)f2bf(f3) << 16);
  o.z = (unsigned int)f2bf(f4) | ((unsigned int)f2bf(f5) << 16);
  o.w = (unsigned int)f2bf(f6) | ((unsigned int)f2bf(f7) << 16);
  *(uint4*)&y1r[(size_t)idx * 8] = o;
}

// ConvTranspose 4x4 s2 p1 via bf16 MFMA, u-block=2. grid 512: bid&7=n, then py, ub.
// 512 threads, 8 waves: px_w = wave>>2, ns = wave&3 (co slice 64).
__global__ __launch_bounds__(512) void k_convt2(const unsigned short* __restrict__ y1b,
                                                const unsigned short* __restrict__ wcb,
                                                float* __restrict__ out) {
  // aLds: [r(3)][c(66)] rows of 40 ushort; wLds: [px(2)][co(256)] rows of 40 ushort
  __shared__ unsigned short sh[3 * 66 * 40 + 2 * 256 * 40]; // 56800 B
  unsigned short* aLds = sh;
  unsigned short* wLds = sh + 3 * 66 * 40;

  int bid = blockIdx.x;
  int n = bid & 7;
  int r2 = bid >> 3;
  int py = r2 & 1;
  int ub = r2 >> 1;        // 0..31
  int u0 = ub * 2;
  int ry0 = u0 - 1 + py;   // rows ry0..ry0+2
  int t = threadIdx.x;
  int wave = t >> 6, lane = t & 63;
  int px_w = wave >> 2, ns = wave & 3;
  int co_base = ns * 64;
  int l15 = lane & 15, l4 = lane >> 4;
  bool rvalid[3];
#pragma unroll
  for (int r = 0; r < 3; ++r) rvalid[r] = (ry0 + r >= 0) && (ry0 + r < 64);

  f32x4 acc[2][4][4] = {};

  for (int chunk = 0; chunk < 8; ++chunk) {
    int ci0 = chunk * 32;
    __syncthreads(); // all prev reads of aLds/wLds done
    // stage A: tasks r(3) x c(66) x slot(4) = 792
    for (int task = t; task < 792; task += 512) {
      int slot = task & 3;
      int rc = task >> 2;
      int c = rc % 66;
      int r = rc / 66;
      int ix = c - 1;
      uint4 val = make_uint4(0u, 0u, 0u, 0u);
      if (rvalid[r] && ix >= 0 && ix < 64)
        val = *(const uint4*)&y1b[((size_t)(n * 4096 + (ry0 + r) * 64 + ix) * 256 + ci0 + slot * 8)];
      *(uint4*)&aLds[(r * 66 + c) * 40 + slot * 8] = val;
    }
    for (int tap = 0; tap < 4; ++tap) {
      if (tap) __syncthreads(); // prev tap's wLds reads done
      // stage W: px(2) x co(256) x slot(4) = 2048
#pragma unroll
      for (int it = 0; it < 4; ++it) {
        int task = it * 512 + t;
        int slot = task & 3;
        int co = (task >> 2) & 255;
        int px = task >> 10;
        const unsigned short* src =
            wcb + ((size_t)((((py * 2 + px) * 4 + tap) * 8 + chunk) * 256 + co) * 32 + slot * 8);
        *(uint4*)&wLds[(px * 256 + co) * 40 + slot * 8] = *(const uint4*)src;
      }
      __syncthreads(); // wLds (and tap0: aLds) ready
      int r_ofs = tap >> 1, s = tap & 1;
      bf16x8 b[4];
#pragma unroll
      for (int j = 0; j < 4; ++j)
        b[j] = *(bf16x8*)&wLds[(px_w * 256 + co_base + 16 * j + l15) * 40 + l4 * 8];
#pragma unroll
      for (int k = 0; k < 2; ++k)
#pragma unroll
        for (int i = 0; i < 4; ++i) {
          int c = 16 * i + l15 + s + px_w;
          bf16x8 a = *(bf16x8*)&aLds[((k + r_ofs) * 66 + c) * 40 + l4 * 8];
#pragma unroll
          for (int j = 0; j < 4; ++j)
            acc[k][i][j] = __builtin_amdgcn_mfma_f32_16x16x32_bf16(a, b[j], acc[k][i][j], 0, 0, 0);
        }
    }
  }

  // epilogue: interleave px via LDS, contiguous 128-float row stores.
  float* epi = (float*)sh;
#pragma unroll
  for (int k = 0; k < 2; ++k) {
    int oy = 2 * (u0 + k) + py;
    for (int qt = 0; qt < 4; ++qt) {
      __syncthreads();
      if (ns == qt) {
#pragma unroll
        for (int i = 0; i < 4; ++i)
#pragma unroll
          for (int j = 0; j < 4; ++j) {
            int co_l = 16 * j + l15;
            int vbase = 16 * i + l4 * 4;
            *(f32x4*)&epi[co_l * 132 + px_w * 64 + vbase] = acc[k][i][j];
          }
      }
      __syncthreads();
#pragma unroll
      for (int it = 0; it < 4; ++it) {
        int task = it * 512 + t;
        int q = task & 31;
        int co_l = task >> 5;
        int co = qt * 64 + co_l;
        float e00 = epi[co_l * 132 + 2 * q];
        float e01 = epi[co_l * 132 + 2 * q + 1];
        float e10 = epi[co_l * 132 + 64 + 2 * q];
        float e11 = epi[co_l * 132 + 64 + 2 * q + 1];
        float4 vv = make_float4(e00, e10, e01, e11);
        *(float4*)&out[((size_t)(n * 256 + co) * 128 + oy) * 128 + 4 * q] = vv;
      }
    }
  }
}

// stats over NCHW buffer, one block per (n,c)x8: 16384 contiguous
__global__ void k_stats_nchw(const float* __restrict__ buf, float* __restrict__ sums) {
  __shared__ float red[256];
  int b = blockIdx.x;
  int c = b & 255;
  int t = threadIdx.x;
  const float* p = buf + (size_t)b * 16384;
  float s = 0.f, q = 0.f;
  for (int i = t; i < 16384; i += 256) {
    float v = p[i];
    s += v; q += v * v;
  }
  red[t] = s; __syncthreads();
  for (int w = 128; w > 0; w >>= 1) { if (t < w) red[t] += red[t + w]; __syncthreads(); }
  float ts = red[0];
  __syncthreads();
  red[t] = q; __syncthreads();
  for (int w = 128; w > 0; w >>= 1) { if (t < w) red[t] += red[t + w]; __syncthreads(); }
  if (t == 0) { atomicAdd(&sums[c], ts); atomicAdd(&sums[256 + c], red[0]); }
}

__global__ void k_norm_nchw(float* __restrict__ buf, const float* __restrict__ scsh) {
  int idx = blockIdx.x * 256 + threadIdx.x; // float4 index
  int c = (idx >> 12) & 255;
  float sc = scsh[c], sh = scsh[256 + c];
  float4 v = *(float4*)&buf[(size_t)idx * 4];
  v.x = fmaxf(fmaf(v.x, sc, sh), 0.f);
  v.y = fmaxf(fmaf(v.y, sc, sh), 0.f);
  v.z = fmaxf(fmaf(v.z, sc, sh), 0.f);
  v.w = fmaxf(fmaf(v.w, sc, sh), 0.f);
  *(float4*)&buf[(size_t)idx * 4] = v;
}

extern "C" void kernel_launch(void* const* d_in, const int* in_sizes, int n_in,
                              void* d_out, int out_size, void* d_ws, size_t ws_size,
                              hipStream_t stream) {
  (void)in_sizes; (void)n_in; (void)out_size; (void)ws_size;
  const float* x      = (const float*)d_in[0];
  const float* w_off  = (const float*)d_in[1];
  const float* b_off  = (const float*)d_in[2];
  const float* w_dcn  = (const float*)d_in[3];
  const float* b_dcn  = (const float*)d_in[4];
  const float* gamma1 = (const float*)d_in[5];
  const float* beta1  = (const float*)d_in[6];
  const float* w_ct   = (const float*)d_in[7];
  const float* gamma2 = (const float*)d_in[8];
  const float* beta2  = (const float*)d_in[9];
  float* ws  = (float*)d_ws;
  unsigned short* xtb = (unsigned short*)(ws + OFF_XT);
  unsigned short* y1r = (unsigned short*)(ws + OFF_Y1);
  float* om  = ws + OFF_OM;
  unsigned short* wdb = (unsigned short*)(ws + OFF_WD);
  unsigned short* wcb = (unsigned short*)(ws + OFF_WC);
  float* st  = ws + OFF_ST;
  float* out = (float*)d_out;

  hipMemsetAsync(st, 0, 2048 * sizeof(float), stream);
  k_init_om<<<3456, 256, 0, stream>>>(b_off, om);
  k_transpose_x<<<dim3(512, 8, 2), 256, 0, stream>>>(x, xtb);
  k_prep_wdcn<<<2304, 256, 0, stream>>>(w_dcn, wdb);
  k_prep_wct<<<4096, 256, 0, stream>>>(w_ct, wcb);
  k_offset_conv<<<dim3(128, 8), 256, 0, stream>>>(x, w_off, om);
  k_dcn2<<<256, 512, 0, stream>>>(xtb, om, wdb, b_dcn, y1r);
  k_stats_b16<<<256, 256, 0, stream>>>(y1r, st);
  k_finalize<<<1, 256, 0, stream>>>(st, gamma1, beta1, st + 512, 1.f / 32768.f);
  k_norm_b16<<<4096, 256, 0, stream>>>(y1r, st + 512);
  k_convt2<<<512, 512, 0, stream>>>(y1r, wcb, out);
  k_stats_nchw<<<2048, 256, 0, stream>>>(out, st + 1024);
  k_finalize<<<1, 256, 0, stream>>>(st + 1024, gamma2, beta2, st + 1536, 1.f / 131072.f);
  k_norm_nchw<<<32768, 256, 0, stream>>>(out, st + 1536);
}

// Round 6
// 337.611 us; speedup vs baseline: 5.3074x; 1.5805x over previous
//
#include <hip/hip_runtime.h>

// Problem constants
// x: (8,256,64,64), w_off:(27,256,3,3), w_dcn:(256,256,3,3), w_ct:(256,256,4,4)
// out: (8,256,128,128) fp32

// ws layout (float offsets)
#define OFF_XT   0u
#define SZ_XT    (8u*64u*64u*256u)          // xtb bf16 NHWC (8.4M ushorts in 33.5MB slot)
#define OFF_Y1   (OFF_XT + SZ_XT)           // y1 raw/normalized bf16 NHWC
#define SZ_Y1    SZ_XT
#define OFF_OM   (OFF_Y1 + SZ_Y1)           // offset-conv out (8,27,64,64)
#define SZ_OM    (8u*27u*4096u)
#define OFF_WD   (OFF_OM + SZ_OM)           // wdb bf16 [k][chunk][co][ci32]
#define SZ_WD    (9u*256u*256u)
#define OFF_WC   (OFF_WD + SZ_WD)           // wcb bf16 packed [py][px][tap][chunk][co][ci32]
#define SZ_WC    (16u*256u*256u)
#define OFF_WO   (OFF_WC + 524288u)         // wob bf16 [tap9][chunk8][co32][ci32] (73728 ushorts)
#define OFF_ST   (OFF_WC + SZ_WC)           // stats: 2048 floats

typedef __attribute__((ext_vector_type(8))) short bf16x8;
typedef __attribute__((ext_vector_type(4))) float f32x4;

__device__ __forceinline__ unsigned short f2bf(float f) {
  unsigned int u = __float_as_uint(f);
  u += 0x7fffu + ((u >> 16) & 1u);
  return (unsigned short)(u >> 16);
}

__device__ __forceinline__ unsigned int lerp_pair(unsigned int u00, unsigned int u01,
                                                  unsigned int u10, unsigned int u11,
                                                  float w0, float w1, float w2, float w3) {
  float lo = w0 * __uint_as_float(u00 << 16) + w1 * __uint_as_float(u01 << 16) +
             w2 * __uint_as_float(u10 << 16) + w3 * __uint_as_float(u11 << 16);
  float hi = w0 * __uint_as_float(u00 & 0xffff0000u) + w1 * __uint_as_float(u01 & 0xffff0000u) +
             w2 * __uint_as_float(u10 & 0xffff0000u) + w3 * __uint_as_float(u11 & 0xffff0000u);
  return (unsigned int)f2bf(lo) | ((unsigned int)f2bf(hi) << 16);
}

// NCHW -> NHWC bf16 transpose of x
__global__ __launch_bounds__(256) void k_transpose_x(const float* __restrict__ x,
                                                     unsigned short* __restrict__ xtb) {
  __shared__ float tile[32][33];
  int ny = blockIdx.x;          // n*64 + y
  int n = ny >> 6, y = ny & 63;
  int c0 = blockIdx.y * 32;
  int w0 = blockIdx.z * 32;
  int t = threadIdx.x;
  int tx = t & 31, ty = t >> 5; // ty 0..7
#pragma unroll
  for (int i = 0; i < 4; ++i) {
    int c = c0 + ty + i * 8;
    tile[ty + i * 8][tx] = x[(((n * 256 + c) * 64 + y) << 6) + w0 + tx];
  }
  __syncthreads();
#pragma unroll
  for (int i = 0; i < 4; ++i) {
    int wl = ty + i * 8;
    xtb[(((n * 64 + y) * 64 + (w0 + wl)) << 8) + c0 + tx] = f2bf(tile[tx][wl]);
  }
}

// w_dcn -> bf16 packed [k][chunk(8)][co(256)][ci 32]
__global__ void k_prep_wdcn(const float* __restrict__ w, unsigned short* __restrict__ wdb) {
  int idx = blockIdx.x * 256 + threadIdx.x;
  if (idx < 589824) {
    int cil = idx & 31;
    int co = (idx >> 5) & 255;
    int chunk = (idx >> 13) & 7;
    int k = idx >> 16;
    int ci = chunk * 32 + cil;
    wdb[idx] = f2bf(w[(co * 256 + ci) * 9 + k]);
  }
}

// w_ct -> bf16 packed [py][px][tap][chunk][co 256][ci 32]
__global__ void k_prep_wct(const float* __restrict__ w, unsigned short* __restrict__ wcb) {
  int idx = blockIdx.x * 256 + threadIdx.x;
  int cil = idx & 31;
  int co = (idx >> 5) & 255;
  int chunk = (idx >> 13) & 7;
  int tap = (idx >> 16) & 3;
  int px = (idx >> 18) & 1;
  int py = (idx >> 19) & 1;
  int ci = chunk * 32 + cil;
  int krA = (py == 0) ? 3 : 2, krB = (py == 0) ? 1 : 0;
  int kc0 = (px == 0) ? 3 : 2, kc1 = kc0 - 2;
  int kr = (tap < 2) ? krA : krB;
  int kc = (tap & 1) ? kc1 : kc0;
  float v = w[(ci << 12) + (co << 4) + kr * 4 + kc];
  wcb[idx] = f2bf(v);
}

// w_off -> bf16 packed [tap(9)][chunk(8)][co 32 (27 padded)][ci 32]
__global__ void k_prep_woff(const float* __restrict__ w, unsigned short* __restrict__ wob) {
  int idx = blockIdx.x * 256 + threadIdx.x; // < 73728
  int cil = idx & 31;
  int co = (idx >> 5) & 31;
  int chunk = (idx >> 10) & 7;
  int tap = idx >> 13;
  int ci = chunk * 32 + cil;
  float v = (co < 27) ? w[(co * 256 + ci) * 9 + tap] : 0.f;
  wob[idx] = f2bf(v);
}

// offset conv 256->27(pad 32) via bf16 MFMA. grid 128: bid&7=n, bid>>3=yq (4 rows).
// 512 threads, 8 waves: wave owns 32 positions (row wave>>1, col half (wave&1)*32).
__global__ __launch_bounds__(512) void k_offset_mfma(const unsigned short* __restrict__ xtb,
                                                     const unsigned short* __restrict__ wob,
                                                     const float* __restrict__ b_off,
                                                     float* __restrict__ om) {
  __shared__ unsigned short aLds[6 * 66 * 40];  // rows ybase-1..ybase+4, cols -1..64
  __shared__ unsigned short wLds[9 * 32 * 40];
  int bid = blockIdx.x;
  int n = bid & 7, yq = bid >> 3;
  int ybase = yq * 4;
  int t = threadIdx.x;
  int wave = t >> 6, lane = t & 63;
  int lr = wave >> 1, cb = (wave & 1) * 32;
  int l15 = lane & 15, l4 = lane >> 4;
  f32x4 acc[2][2] = {};

  for (int chunk = 0; chunk < 8; ++chunk) {
    __syncthreads();
    // stage A: 6 rows x 66 cols x 4 slots = 1584 tasks
    for (int task = t; task < 1584; task += 512) {
      int slot = task & 3;
      int rc = task >> 2;
      int c = rc % 66, r = rc / 66;
      int gy = ybase - 1 + r, gx = c - 1;
      uint4 val = make_uint4(0u, 0u, 0u, 0u);
      if (gy >= 0 && gy < 64 && gx >= 0 && gx < 64)
        val = *(const uint4*)&xtb[((size_t)(n * 4096 + gy * 64 + gx) << 8) + chunk * 32 + slot * 8];
      *(uint4*)&aLds[(r * 66 + c) * 40 + slot * 8] = val;
    }
    // stage B: 9 taps x 32 co x 4 slots = 1152 tasks
    for (int task = t; task < 1152; task += 512) {
      int sl = task & 3;
      int co = (task >> 2) & 31;
      int tap = task >> 7;
      *(uint4*)&wLds[(tap * 32 + co) * 40 + sl * 8] =
          *(const uint4*)&wob[(size_t)((tap * 8 + chunk) * 32 + co) * 32 + sl * 8];
    }
    __syncthreads();
#pragma unroll
    for (int ky = 0; ky < 3; ++ky)
#pragma unroll
      for (int kx = 0; kx < 3; ++kx) {
        int tap = ky * 3 + kx;
        bf16x8 b0 = *(bf16x8*)&wLds[(tap * 32 + l15) * 40 + l4 * 8];
        bf16x8 b1 = *(bf16x8*)&wLds[(tap * 32 + 16 + l15) * 40 + l4 * 8];
        bf16x8 a0 = *(bf16x8*)&aLds[((lr + ky) * 66 + cb + l15 + kx) * 40 + l4 * 8];
        bf16x8 a1 = *(bf16x8*)&aLds[((lr + ky) * 66 + cb + 16 + l15 + kx) * 40 + l4 * 8];
        acc[0][0] = __builtin_amdgcn_mfma_f32_16x16x32_bf16(a0, b0, acc[0][0], 0, 0, 0);
        acc[0][1] = __builtin_amdgcn_mfma_f32_16x16x32_bf16(a0, b1, acc[0][1], 0, 0, 0);
        acc[1][0] = __builtin_amdgcn_mfma_f32_16x16x32_bf16(a1, b0, acc[1][0], 0, 0, 0);
        acc[1][1] = __builtin_amdgcn_mfma_f32_16x16x32_bf16(a1, b1, acc[1][1], 0, 0, 0);
      }
  }
  // epilogue: bias + direct float4 store into om (no atomics, no init kernel)
  int row = ybase + lr;
#pragma unroll
  for (int j = 0; j < 2; ++j) {
    int co = 16 * j + l15;
    if (co < 27) {
      float bias = b_off[co];
      float* dst = om + ((size_t)(n * 27 + co) << 12) + row * 64;
#pragma unroll
      for (int i = 0; i < 2; ++i) {
        f32x4 v = acc[i][j];
        float4 o = make_float4(v[0] + bias, v[1] + bias, v[2] + bias, v[3] + bias);
        *(float4*)&dst[cb + 16 * i + l4 * 4] = o;
      }
    }
  }
}

// DCN v2 via bf16 MFMA, y-pair blocks. grid 256: bid&7 = n (XCD affinity), bid>>3 = ypair.
__global__ __launch_bounds__(512) void k_dcn2(const unsigned short* __restrict__ xtb,
                                              const float* __restrict__ om,
                                              const unsigned short* __restrict__ wdb,
                                              const float* __restrict__ b_dcn,
                                              unsigned short* __restrict__ y1r) {
  __shared__ unsigned short aLds[128 * 40];  // [pos][32ci + 8 pad]
  __shared__ unsigned short wLds[256 * 40];  // [co][32ci + 8 pad]
  __shared__ int p_y0[128], p_y1[128], p_x0[128], p_x1[128];
  __shared__ float p_w[128][4];
  int bid = blockIdx.x;
  int n = bid & 7, yp = bid >> 3;
  int ybase = yp * 2;
  int t = threadIdx.x;
  int wave = t >> 6, lane = t & 63;
  int mh = wave >> 2, ns = wave & 3;
  int l15 = lane & 15, l4 = lane >> 4;
  int gp = t >> 2, gq = t & 3; // gather roles: pos, ci-oct
  f32x4 acc[4][4] = {};

  for (int tap = 0; tap < 9; ++tap) {
    int ki = tap / 3, kj = tap % 3;
    __syncthreads(); // prev tap LDS reads + p_* reads done
    if (t < 128) {
      int pp = t;
      int yy = ybase + (pp >> 6), xx = pp & 63;
      const float* base = om + (n * 27) * 4096 + (yy << 6) + xx;
      float offy = base[(2 * tap) * 4096];
      float offx = base[(2 * tap + 1) * 4096];
      float mv = base[(18 + tap) * 4096];
      float mask = 1.f / (1.f + expf(-mv));
      float ysf = (float)(yy + ki - 1) + offy;
      float xsf = (float)(xx + kj - 1) + offx;
      float y0f = floorf(ysf), x0f = floorf(xsf);
      float dy = ysf - y0f, dx = xsf - x0f;
      int y0 = (int)y0f, x0 = (int)x0f;
      int y1c = y0 + 1, x1c = x0 + 1;
      float v00 = (y0 >= 0 && y0 < 64 && x0 >= 0 && x0 < 64) ? 1.f : 0.f;
      float v01 = (y0 >= 0 && y0 < 64 && x1c >= 0 && x1c < 64) ? 1.f : 0.f;
      float v10 = (y1c >= 0 && y1c < 64 && x0 >= 0 && x0 < 64) ? 1.f : 0.f;
      float v11 = (y1c >= 0 && y1c < 64 && x1c >= 0 && x1c < 64) ? 1.f : 0.f;
      p_y0[pp] = min(max(y0, 0), 63);
      p_y1[pp] = min(max(y1c, 0), 63);
      p_x0[pp] = min(max(x0, 0), 63);
      p_x1[pp] = min(max(x1c, 0), 63);
      p_w[pp][0] = (1.f - dy) * (1.f - dx) * mask * v00;
      p_w[pp][1] = (1.f - dy) * dx * mask * v01;
      p_w[pp][2] = dy * (1.f - dx) * mask * v10;
      p_w[pp][3] = dy * dx * mask * v11;
    }
    __syncthreads(); // p_* ready
    int y0 = p_y0[gp], y1c = p_y1[gp], x0 = p_x0[gp], x1c = p_x1[gp];
    float w0 = p_w[gp][0], w1 = p_w[gp][1], w2 = p_w[gp][2], w3 = p_w[gp][3];
    int nb = n << 12;
    const unsigned short* b00 = xtb + ((size_t)(nb + (y0 << 6) + x0) << 8) + gq * 8;
    const unsigned short* b01 = xtb + ((size_t)(nb + (y0 << 6) + x1c) << 8) + gq * 8;
    const unsigned short* b10 = xtb + ((size_t)(nb + (y1c << 6) + x0) << 8) + gq * 8;
    const unsigned short* b11 = xtb + ((size_t)(nb + (y1c << 6) + x1c) << 8) + gq * 8;
    const unsigned short* wsrc = wdb + (size_t)tap * 65536;
    for (int chunk = 0; chunk < 8; ++chunk) {
      if (chunk) __syncthreads(); // prev chunk MFMA reads done
      // stage W: 256co x 32ci
      {
        const unsigned short* wp = wsrc + chunk * 8192;
#pragma unroll
        for (int it = 0; it < 2; ++it) {
          int task = it * 512 + t;
          int co = task >> 2, sl = task & 3;
          *(uint4*)&wLds[co * 40 + sl * 8] = *(const uint4*)&wp[co * 32 + sl * 8];
        }
      }
      // gather A: 128 pos x 32 ci (8 per thread), bf16 corners
      {
        int cio = chunk * 32;
        uint4 c00 = *(const uint4*)(b00 + cio);
        uint4 c01 = *(const uint4*)(b01 + cio);
        uint4 c10 = *(const uint4*)(b10 + cio);
        uint4 c11 = *(const uint4*)(b11 + cio);
        uint4 o;
        o.x = lerp_pair(c00.x, c01.x, c10.x, c11.x, w0, w1, w2, w3);
        o.y = lerp_pair(c00.y, c01.y, c10.y, c11.y, w0, w1, w2, w3);
        o.z = lerp_pair(c00.z, c01.z, c10.z, c11.z, w0, w1, w2, w3);
        o.w = lerp_pair(c00.w, c01.w, c10.w, c11.w, w0, w1, w2, w3);
        *(uint4*)&aLds[gp * 40 + gq * 8] = o;
      }
      __syncthreads();
      bf16x8 b[4], a[4];
#pragma unroll
      for (int j = 0; j < 4; ++j)
        b[j] = *(bf16x8*)&wLds[(ns * 64 + 16 * j + l15) * 40 + l4 * 8];
#pragma unroll
      for (int i = 0; i < 4; ++i)
        a[i] = *(bf16x8*)&aLds[(mh * 64 + 16 * i + l15) * 40 + l4 * 8];
#pragma unroll
      for (int i = 0; i < 4; ++i)
#pragma unroll
        for (int j = 0; j < 4; ++j)
          acc[i][j] = __builtin_amdgcn_mfma_f32_16x16x32_bf16(a[i], b[j], acc[i][j], 0, 0, 0);
    }
  }
  // epilogue: bias + bf16 store (NHWC)
  unsigned short* dst = y1r + ((size_t)(n * 4096 + ybase * 64) << 8);
#pragma unroll
  for (int j = 0; j < 4; ++j) {
    int co = ns * 64 + 16 * j + l15;
    float bias = b_dcn[co];
#pragma unroll
    for (int i = 0; i < 4; ++i)
#pragma unroll
      for (int rr = 0; rr < 4; ++rr) {
        int pos = mh * 64 + 16 * i + l4 * 4 + rr;
        dst[pos * 256 + co] = f2bf(acc[i][j][rr] + bias);
      }
  }
}

// BN1 stats over bf16 NHWC buffer: 256 blocks x 128 rows; thread t owns co=t.
__global__ __launch_bounds__(256) void k_stats_b16(const unsigned short* __restrict__ y1r,
                                                   float* __restrict__ sums) {
  int t = threadIdx.x;
  int r0 = blockIdx.x * 128;
  float s = 0.f, q = 0.f;
  const unsigned short* p = y1r + (size_t)r0 * 256 + t;
  for (int r = 0; r < 128; ++r) {
    float v = __uint_as_float(((unsigned int)p[r * 256]) << 16);
    s += v; q += v * v;
  }
  atomicAdd(&sums[t], s);
  atomicAdd(&sums[256 + t], q);
}

__global__ void k_finalize(const float* __restrict__ sums, const float* __restrict__ gamma,
                           const float* __restrict__ beta, float* __restrict__ scsh,
                           float inv_cnt) {
  int t = threadIdx.x;
  float mu = sums[t] * inv_cnt;
  float var = sums[256 + t] * inv_cnt - mu * mu;
  float r = rsqrtf(var + 1e-5f);
  float sc = gamma[t] * r;
  scsh[t] = sc;
  scsh[256 + t] = beta[t] - mu * sc;
}

// normalize+relu in place on bf16 NHWC buffer
__global__ void k_norm_b16(unsigned short* __restrict__ y1r, const float* __restrict__ scsh) {
  int idx = blockIdx.x * 256 + threadIdx.x; // uint4 index (8 bf16)
  int cb = (idx & 31) * 8;
  uint4 v = *(uint4*)&y1r[(size_t)idx * 8];
  float4 sc0 = *(const float4*)&scsh[cb];
  float4 sc1 = *(const float4*)&scsh[cb + 4];
  float4 sh0 = *(const float4*)&scsh[256 + cb];
  float4 sh1 = *(const float4*)&scsh[256 + cb + 4];
  float f0 = __uint_as_float(v.x << 16), f1 = __uint_as_float(v.x & 0xffff0000u);
  float f2 = __uint_as_float(v.y << 16), f3 = __uint_as_float(v.y & 0xffff0000u);
  float f4 = __uint_as_float(v.z << 16), f5 = __uint_as_float(v.z & 0xffff0000u);
  float f6 = __uint_as_float(v.w << 16), f7 = __uint_as_float(v.w & 0xffff0000u);
  f0 = fmaxf(fmaf(f0, sc0.x, sh0.x), 0.f); f1 = fmaxf(fmaf(f1, sc0.y, sh0.y), 0.f);
  f2 = fmaxf(fmaf(f2, sc0.z, sh0.z), 0.f); f3 = fmaxf(fmaf(f3, sc0.w, sh0.w), 0.f);
  f4 = fmaxf(fmaf(f4, sc1.x, sh1.x), 0.f); f5 = fmaxf(fmaf(f5, sc1.y, sh1.y), 0.f);
  f6 = fmaxf(fmaf(f6, sc1.z, sh1.z), 0.f); f7 = fmaxf(fmaf(f7, sc1.w, sh1.w), 0.f);
  uint4 o;
  o.x = (unsigned int)f2bf(f0) | ((unsigned int)f2bf(f1) << 16);
  o.y = (unsigned int)f2bf(f2) | ((unsigned int)f2bf(f3) << 16);
  o.z = (unsigned int)f2bf(f4) | ((unsigned int)f2bf(f5) << 16);
  o.w = (unsigned int)f2bf(f6) | ((unsigned int)f2bf(f7) << 16);
  *(uint4*)&y1r[(size_t)idx * 8] = o;
}

// ConvTranspose 4x4 s2 p1 via bf16 MFMA, u-block=2. grid 512: bid&7=n, then py, ub.
__global__ __launch_bounds__(512) void k_convt2(const unsigned short* __restrict__ y1b,
                                                const unsigned short* __restrict__ wcb,
                                                float* __restrict__ out) {
  __shared__ unsigned short sh[3 * 66 * 40 + 2 * 256 * 40]; // 56800 B
  unsigned short* aLds = sh;
  unsigned short* wLds = sh + 3 * 66 * 40;

  int bid = blockIdx.x;
  int n = bid & 7;
  int r2 = bid >> 3;
  int py = r2 & 1;
  int ub = r2 >> 1;        // 0..31
  int u0 = ub * 2;
  int ry0 = u0 - 1 + py;   // rows ry0..ry0+2
  int t = threadIdx.x;
  int wave = t >> 6, lane = t & 63;
  int px_w = wave >> 2, ns = wave & 3;
  int co_base = ns * 64;
  int l15 = lane & 15, l4 = lane >> 4;
  bool rvalid[3];
#pragma unroll
  for (int r = 0; r < 3; ++r) rvalid[r] = (ry0 + r >= 0) && (ry0 + r < 64);

  f32x4 acc[2][4][4] = {};

  for (int chunk = 0; chunk < 8; ++chunk) {
    int ci0 = chunk * 32;
    __syncthreads(); // all prev reads of aLds/wLds done
    // stage A: tasks r(3) x c(66) x slot(4) = 792
    for (int task = t; task < 792; task += 512) {
      int slot = task & 3;
      int rc = task >> 2;
      int c = rc % 66;
      int r = rc / 66;
      int ix = c - 1;
      uint4 val = make_uint4(0u, 0u, 0u, 0u);
      if (rvalid[r] && ix >= 0 && ix < 64)
        val = *(const uint4*)&y1b[((size_t)(n * 4096 + (ry0 + r) * 64 + ix) * 256 + ci0 + slot * 8)];
      *(uint4*)&aLds[(r * 66 + c) * 40 + slot * 8] = val;
    }
    for (int tap = 0; tap < 4; ++tap) {
      if (tap) __syncthreads(); // prev tap's wLds reads done
      // stage W: px(2) x co(256) x slot(4) = 2048
#pragma unroll
      for (int it = 0; it < 4; ++it) {
        int task = it * 512 + t;
        int slot = task & 3;
        int co = (task >> 2) & 255;
        int px = task >> 10;
        const unsigned short* src =
            wcb + ((size_t)((((py * 2 + px) * 4 + tap) * 8 + chunk) * 256 + co) * 32 + slot * 8);
        *(uint4*)&wLds[(px * 256 + co) * 40 + slot * 8] = *(const uint4*)src;
      }
      __syncthreads(); // wLds (and tap0: aLds) ready
      int r_ofs = tap >> 1, s = tap & 1;
      bf16x8 b[4];
#pragma unroll
      for (int j = 0; j < 4; ++j)
        b[j] = *(bf16x8*)&wLds[(px_w * 256 + co_base + 16 * j + l15) * 40 + l4 * 8];
#pragma unroll
      for (int k = 0; k < 2; ++k)
#pragma unroll
        for (int i = 0; i < 4; ++i) {
          int c = 16 * i + l15 + s + px_w;
          bf16x8 a = *(bf16x8*)&aLds[((k + r_ofs) * 66 + c) * 40 + l4 * 8];
#pragma unroll
          for (int j = 0; j < 4; ++j)
            acc[k][i][j] = __builtin_amdgcn_mfma_f32_16x16x32_bf16(a, b[j], acc[k][i][j], 0, 0, 0);
        }
    }
  }

  // epilogue: interleave px via LDS, contiguous 128-float row stores.
  float* epi = (float*)sh;
#pragma unroll
  for (int k = 0; k < 2; ++k) {
    int oy = 2 * (u0 + k) + py;
    for (int qt = 0; qt < 4; ++qt) {
      __syncthreads();
      if (ns == qt) {
#pragma unroll
        for (int i = 0; i < 4; ++i)
#pragma unroll
          for (int j = 0; j < 4; ++j) {
            int co_l = 16 * j + l15;
            int vbase = 16 * i + l4 * 4;
            *(f32x4*)&epi[co_l * 132 + px_w * 64 + vbase] = acc[k][i][j];
          }
      }
      __syncthreads();
#pragma unroll
      for (int it = 0; it < 4; ++it) {
        int task = it * 512 + t;
        int q = task & 31;
        int co_l = task >> 5;
        int co = qt * 64 + co_l;
        float e00 = epi[co_l * 132 + 2 * q];
        float e01 = epi[co_l * 132 + 2 * q + 1];
        float e10 = epi[co_l * 132 + 64 + 2 * q];
        float e11 = epi[co_l * 132 + 64 + 2 * q + 1];
        float4 vv = make_float4(e00, e10, e01, e11);
        *(float4*)&out[((size_t)(n * 256 + co) * 128 + oy) * 128 + 4 * q] = vv;
      }
    }
  }
}

// stats over NCHW buffer, one block per (n,c): 16384 contiguous
__global__ void k_stats_nchw(const float* __restrict__ buf, float* __restrict__ sums) {
  __shared__ float red[256];
  int b = blockIdx.x;
  int c = b & 255;
  int t = threadIdx.x;
  const float* p = buf + (size_t)b * 16384;
  float s = 0.f, q = 0.f;
  for (int i = t; i < 16384; i += 256) {
    float v = p[i];
    s += v; q += v * v;
  }
  red[t] = s; __syncthreads();
  for (int w = 128; w > 0; w >>= 1) { if (t < w) red[t] += red[t + w]; __syncthreads(); }
  float ts = red[0];
  __syncthreads();
  red[t] = q; __syncthreads();
  for (int w = 128; w > 0; w >>= 1) { if (t < w) red[t] += red[t + w]; __syncthreads(); }
  if (t == 0) { atomicAdd(&sums[c], ts); atomicAdd(&sums[256 + c], red[0]); }
}

__global__ void k_norm_nchw(float* __restrict__ buf, const float* __restrict__ scsh) {
  int idx = blockIdx.x * 256 + threadIdx.x; // float4 index
  int c = (idx >> 12) & 255;
  float sc = scsh[c], sh = scsh[256 + c];
  float4 v = *(float4*)&buf[(size_t)idx * 4];
  v.x = fmaxf(fmaf(v.x, sc, sh), 0.f);
  v.y = fmaxf(fmaf(v.y, sc, sh), 0.f);
  v.z = fmaxf(fmaf(v.z, sc, sh), 0.f);
  v.w = fmaxf(fmaf(v.w, sc, sh), 0.f);
  *(float4*)&buf[(size_t)idx * 4] = v;
}

extern "C" void kernel_launch(void* const* d_in, const int* in_sizes, int n_in,
                              void* d_out, int out_size, void* d_ws, size_t ws_size,
                              hipStream_t stream) {
  (void)in_sizes; (void)n_in; (void)out_size; (void)ws_size;
  const float* x      = (const float*)d_in[0];
  const float* w_off  = (const float*)d_in[1];
  const float* b_off  = (const float*)d_in[2];
  const float* w_dcn  = (const float*)d_in[3];
  const float* b_dcn  = (const float*)d_in[4];
  const float* gamma1 = (const float*)d_in[5];
  const float* beta1  = (const float*)d_in[6];
  const float* w_ct   = (const float*)d_in[7];
  const float* gamma2 = (const float*)d_in[8];
  const float* beta2  = (const float*)d_in[9];
  float* ws  = (float*)d_ws;
  unsigned short* xtb = (unsigned short*)(ws + OFF_XT);
  unsigned short* y1r = (unsigned short*)(ws + OFF_Y1);
  float* om  = ws + OFF_OM;
  unsigned short* wdb = (unsigned short*)(ws + OFF_WD);
  unsigned short* wcb = (unsigned short*)(ws + OFF_WC);
  unsigned short* wob = (unsigned short*)(ws + OFF_WO);
  float* st  = ws + OFF_ST;
  float* out = (float*)d_out;

  hipMemsetAsync(st, 0, 2048 * sizeof(float), stream);
  k_transpose_x<<<dim3(512, 8, 2), 256, 0, stream>>>(x, xtb);
  k_prep_wdcn<<<2304, 256, 0, stream>>>(w_dcn, wdb);
  k_prep_wct<<<4096, 256, 0, stream>>>(w_ct, wcb);
  k_prep_woff<<<288, 256, 0, stream>>>(w_off, wob);
  k_offset_mfma<<<128, 512, 0, stream>>>(xtb, wob, b_off, om);
  k_dcn2<<<256, 512, 0, stream>>>(xtb, om, wdb, b_dcn, y1r);
  k_stats_b16<<<256, 256, 0, stream>>>(y1r, st);
  k_finalize<<<1, 256, 0, stream>>>(st, gamma1, beta1, st + 512, 1.f / 32768.f);
  k_norm_b16<<<4096, 256, 0, stream>>>(y1r, st + 512);
  k_convt2<<<512, 512, 0, stream>>>(y1r, wcb, out);
  k_stats_nchw<<<2048, 256, 0, stream>>>(out, st + 1024);
  k_finalize<<<1, 256, 0, stream>>>(st + 1024, gamma2, beta2, st + 1536, 1.f / 131072.f);
  k_norm_nchw<<<32768, 256, 0, stream>>>(out, st + 1536);
}